// Round 12
// baseline (251.684 us; speedup 1.0000x reference)
//
#include <hip/hip_runtime.h>
#include <hip/hip_bf16.h>
#include <math.h>

#define BATCH 2
#define CC    256
#define NN    4096
#define KK    409          // max(1, int(0.1*4096))
#define KCAT  768          // split-fp16 concat K (compensated product — REQUIRED,
                           // r5 showed dropping it fails tolerance: 0.0127 > 0.0117)
#define SCALE 0.0625f      // 1/sqrt(256)
#define PSTRIDE 4096       // P row stride in halfs (P row aliases fp16 S row exactly)

typedef _Float16 half8 __attribute__((ext_vector_type(8)));
typedef float    floatx4 __attribute__((ext_vector_type(4)));

// async global->LDS, 16B per lane; LDS dest = wave-uniform base + lane*16
typedef __attribute__((address_space(3))) unsigned       lds_u32;
typedef __attribute__((address_space(1))) const unsigned glb_u32;
__device__ __forceinline__ void gload16(const void* g, void* l) {
    __builtin_amdgcn_global_load_lds((glb_u32*)g, (lds_u32*)l, 16, 0, 0);
}

// ---------- kernel 1: xpose (by<4) + wcat (by==4) merged ----------
__global__ __launch_bounds__(256) void xpose_wcat_kernel(
        const float* __restrict__ x,
        const float* __restrict__ Wq, const float* __restrict__ Wk,
        const float* __restrict__ Wv,
        _Float16* __restrict__ xcat, _Float16* __restrict__ Wcat) {
    const int t  = threadIdx.x;
    if (blockIdx.y == 4) {
        int idx = (blockIdx.z * 64 + blockIdx.x) * 256 + t;
#pragma unroll
        for (int k = 0; k < 6; k++) {
            int e = idx + k * 32768;              // covers 3*65536 exactly
            int mat = e >> 16;
            int o   = (e >> 8) & 255;
            int c   = e & 255;
            const float* W = (mat == 0) ? Wq : (mat == 1) ? Wk : Wv;
            float v = W[o * 256 + c];
            _Float16 hi = (_Float16)v;
            _Float16 lo = (_Float16)(v - (float)hi);
            _Float16* wr = Wcat + ((size_t)(mat * 256 + o)) * KCAT;
            wr[c] = hi; wr[256 + c] = hi; wr[512 + c] = lo;
        }
        return;
    }

    __shared__ float xs[64][68];
    const int n0 = blockIdx.x * 64;
    const int c0 = blockIdx.y * 64;
    const int b  = blockIdx.z;

    {
        const int ci = t >> 2;
        const int j  = (t & 3) * 16;
        const float* xp = x + ((size_t)((b << 8) + c0 + ci)) * NN + n0 + j;
        float4 a0 = ((const float4*)xp)[0];
        float4 a1 = ((const float4*)xp)[1];
        float4 a2 = ((const float4*)xp)[2];
        float4 a3 = ((const float4*)xp)[3];
        *(float4*)&xs[ci][j]      = a0;
        *(float4*)&xs[ci][j + 4]  = a1;
        *(float4*)&xs[ci][j + 8]  = a2;
        *(float4*)&xs[ci][j + 12] = a3;
    }
    __syncthreads();

    const int n = t >> 2;
    const int g0 = t & 3;
    _Float16* xr = xcat + ((size_t)(b * NN + n0 + n)) * KCAT + c0;
#pragma unroll
    for (int gg = 0; gg < 2; gg++) {
        int g = g0 + gg * 4;
        half8 hi, lo;
#pragma unroll
        for (int k = 0; k < 8; k++) {
            float v = xs[g * 8 + k][n];
            _Float16 h = (_Float16)v;
            hi[k] = h;
            lo[k] = (_Float16)(v - (float)h);
        }
        *(half8*)(xr + g * 8)       = hi;
        *(half8*)(xr + 256 + g * 8) = lo;
        *(half8*)(xr + 512 + g * 8) = hi;
    }
}

// ---------- kernel 2: projections via MFMA, 128x128 tile, K=768 ----------
// 2-phase double-buffered; compensated split (KCAT=768) throughout. FROZEN
// (already issue-early/drain-late; counted-vmcnt has little to recover here).
__global__ __launch_bounds__(256) void proj_gemm(
        const _Float16* __restrict__ xcat, const _Float16* __restrict__ Wcat,
        const float* __restrict__ bq, const float* __restrict__ bk,
        const float* __restrict__ bv,
        _Float16* __restrict__ Qcat, _Float16* __restrict__ Kcat,
        _Float16* __restrict__ Vt) {
    __shared__ _Float16 As[2][128][64];
    __shared__ _Float16 Bs[2][128][64];

    const int t    = threadIdx.x;
    const int wave = t >> 6;
    const int l    = t & 63;
    const int wr   = wave >> 1;
    const int wc   = wave & 1;
    const int mat  = blockIdx.z;

    int bym, bxn;
    if (mat < 2) { bym = blockIdx.x >> 1; bxn = blockIdx.x & 1; }
    else         { bym = blockIdx.x & 1;  bxn = blockIdx.x >> 1; }

    const int lr = l >> 3;
    const int gg = (l & 7) ^ lr;

    const _Float16* At;
    const _Float16* Bt;
    if (mat < 2) {
        At = xcat + ((size_t)(bym * 128)) * KCAT;
        Bt = Wcat + ((size_t)(mat * 256 + bxn * 128)) * KCAT;
    } else {
        At = Wcat + ((size_t)(512 + bym * 128)) * KCAT;
        Bt = xcat + ((size_t)(bxn * 128)) * KCAT;
    }
    const size_t lane_off = (size_t)lr * KCAT + gg * 8;

    floatx4 acc[4][4];
#pragma unroll
    for (int i = 0; i < 4; i++)
#pragma unroll
        for (int j = 0; j < 4; j++) acc[i][j] = (floatx4)0.0f;

    const int rowA = l & 15;
    const int sg0  = (l >> 4) ^ (l & 7);
    const int sg1  = sg0 ^ 4;

    // prologue: stage K-tile 0
#pragma unroll
    for (int s = 0; s < 4; s++) {
        const int seg = wave * 4 + s;
        gload16(At + (size_t)seg * 8 * KCAT + lane_off, &As[0][seg * 8][0]);
        gload16(Bt + (size_t)seg * 8 * KCAT + lane_off, &Bs[0][seg * 8][0]);
    }
    __syncthreads();

    for (int kt = 0; kt < 12; ++kt) {
        const int cur = kt & 1;
        if (kt < 11) {
            const int kc = (kt + 1) * 64;
#pragma unroll
            for (int s = 0; s < 4; s++) {
                const int seg = wave * 4 + s;
                gload16(At + (size_t)seg * 8 * KCAT + lane_off + kc,
                        &As[cur ^ 1][seg * 8][0]);
                gload16(Bt + (size_t)seg * 8 * KCAT + lane_off + kc,
                        &Bs[cur ^ 1][seg * 8][0]);
            }
        }
#pragma unroll
        for (int ks = 0; ks < 2; ks++) {
            const int sg = ks ? sg1 : sg0;
            half8 af[4], bf[4];
#pragma unroll
            for (int mi = 0; mi < 4; mi++)
                af[mi] = *(const half8*)&As[cur][wr * 64 + mi * 16 + rowA][sg * 8];
#pragma unroll
            for (int ni = 0; ni < 4; ni++)
                bf[ni] = *(const half8*)&Bs[cur][wc * 64 + ni * 16 + rowA][sg * 8];
#pragma unroll
            for (int mi = 0; mi < 4; mi++)
#pragma unroll
                for (int ni = 0; ni < 4; ni++)
                    acc[mi][ni] = __builtin_amdgcn_mfma_f32_16x16x32_f16(
                        af[mi], bf[ni], acc[mi][ni], 0, 0, 0);
        }
        __syncthreads();
    }

    if (mat < 2) {
        const float* bias = (mat == 0) ? bq : bk;
        _Float16* Out = (mat == 0) ? Qcat : Kcat;
#pragma unroll
        for (int ni = 0; ni < 4; ni++) {
            int ch = bxn * 128 + wc * 64 + ni * 16 + (l & 15);
            float bb = bias[ch];
#pragma unroll
            for (int mi = 0; mi < 4; mi++)
#pragma unroll
                for (int rg = 0; rg < 4; rg++) {
                    int token = bym * 128 + wr * 64 + mi * 16 + (l >> 4) * 4 + rg;
                    float v = acc[mi][ni][rg] + bb;
                    _Float16 hi = (_Float16)v;
                    _Float16 lo = (_Float16)(v - (float)hi);
                    _Float16* p = Out + (size_t)token * KCAT + ch;
                    if (mat == 0) { p[0] = hi; p[256] = lo; p[512] = hi; }
                    else          { p[0] = hi; p[256] = hi; p[512] = lo; }
                }
        }
    } else {
#pragma unroll
        for (int mi = 0; mi < 4; mi++)
#pragma unroll
            for (int rg = 0; rg < 4; rg++) {
                int ch = bym * 128 + wr * 64 + mi * 16 + (l >> 4) * 4 + rg;
                float bb = bv[ch];
#pragma unroll
                for (int ni = 0; ni < 4; ni++) {
                    int col = bxn * 128 + wc * 64 + ni * 16 + (l & 15);
                    int b = col >> 12, n = col & 4095;
                    Vt[((size_t)((b << 8) + ch)) * NN + n] =
                        (_Float16)(acc[mi][ni][rg] + bb);
                }
            }
    }
}

// ---------- kernel 3: S = (Qcat @ Kcat^T) * SCALE via MFMA f16, fp16 S ----------
// r11-proven counted-vmcnt 2-phase: BK=64 double-buffer (128 KB LDS),
// stage-next FIRST, vmcnt(8) keeps next-tile loads in flight across the
// barrier. Dropped score out of top-5 in r11. FROZEN.
__global__ __launch_bounds__(512, 2) void score_gemm(
        const _Float16* __restrict__ Qcat, const _Float16* __restrict__ Kcat,
        _Float16* __restrict__ S) {
    __shared__ _Float16 As[2][256][64];   // 64 KB
    __shared__ _Float16 Bs[2][256][64];   // 64 KB

    const int t    = threadIdx.x;
    const int wave = t >> 6;             // 0..7
    const int l    = t & 63;
    const int wr   = wave >> 1;          // 0..3 (M)
    const int wc   = wave & 1;           // 0..1 (N)

    const int id  = blockIdx.x;
    const int sc  = id & 7;              // supercell == XCD (id%8 round-robin)
    const int j   = id >> 3;             // 0..63 within supercell
    const int b   = sc & 1;
    const int scq = sc >> 1;             // quadrant 0..3
    const int bxn = ((scq & 1) << 3) + (j & 7);
    const int bym = ((scq >> 1) << 3) + (j >> 3);

    const int lr = l >> 3;
    const int gg = (l & 7) ^ lr;

    const _Float16* At = Qcat + ((size_t)((b << 12) + bym * 256)) * KCAT;
    const _Float16* Bt = Kcat + ((size_t)((b << 12) + bxn * 256)) * KCAT;
    const size_t lane_off = (size_t)lr * KCAT + gg * 8;

    floatx4 acc[4][8];
#pragma unroll
    for (int i = 0; i < 4; i++)
#pragma unroll
        for (int jj = 0; jj < 8; jj++) acc[i][jj] = (floatx4)0.0f;

    const int rowA = l & 15;
    const int sg0  = (l >> 4) ^ (l & 7);
    const int sg1  = sg0 ^ 4;

    // prologue: issue K-tile 0 loads into buffer 0 (no wait here)
#pragma unroll
    for (int s = 0; s < 4; s++) {
        const int seg = wave * 4 + s;
        gload16(At + (size_t)seg * 8 * KCAT + lane_off, &As[0][seg * 8][0]);
        gload16(Bt + (size_t)seg * 8 * KCAT + lane_off, &Bs[0][seg * 8][0]);
    }

    for (int kt = 0; kt < 12; ++kt) {
        const int cur = kt & 1;
        // stage tile kt+1 into the other buffer (8 gload16 / thread)
        if (kt < 11) {
            const int kc = (kt + 1) * 64;
#pragma unroll
            for (int s = 0; s < 4; s++) {
                const int seg = wave * 4 + s;
                gload16(At + (size_t)seg * 8 * KCAT + lane_off + kc,
                        &As[cur ^ 1][seg * 8][0]);
                gload16(Bt + (size_t)seg * 8 * KCAT + lane_off + kc,
                        &Bs[cur ^ 1][seg * 8][0]);
            }
            // outstanding = 8 (tile kt) + 8 (tile kt+1); retire the oldest 8
            asm volatile("s_waitcnt vmcnt(8)" ::: "memory");
        } else {
            asm volatile("s_waitcnt vmcnt(0)" ::: "memory");
        }
        __builtin_amdgcn_s_barrier();          // all waves' tile-kt segs ready
        asm volatile("" ::: "memory");

#pragma unroll
        for (int ks = 0; ks < 2; ks++) {
            const int sg = ks ? sg1 : sg0;
            half8 af[4], bf[8];
#pragma unroll
            for (int mi = 0; mi < 4; mi++)
                af[mi] = *(const half8*)&As[cur][wr * 64 + mi * 16 + rowA][sg * 8];
#pragma unroll
            for (int ni = 0; ni < 8; ni++)
                bf[ni] = *(const half8*)&Bs[cur][wc * 128 + ni * 16 + rowA][sg * 8];
#pragma unroll
            for (int mi = 0; mi < 4; mi++)
#pragma unroll
                for (int ni = 0; ni < 8; ni++)
                    acc[mi][ni] = __builtin_amdgcn_mfma_f32_16x16x32_f16(
                        af[mi], bf[ni], acc[mi][ni], 0, 0, 0);
        }
        __builtin_amdgcn_s_barrier();          // reads of buf[cur] done before
        asm volatile("" ::: "memory");         // next iter overwrites it
    }

    _Float16* Sb = S + ((size_t)b << 24);   // NN*NN halfs per batch
#pragma unroll
    for (int mi = 0; mi < 4; mi++)
#pragma unroll
        for (int ni = 0; ni < 8; ni++) {
            int col = bxn * 256 + wc * 128 + ni * 16 + (l & 15);
#pragma unroll
            for (int rg = 0; rg < 4; rg++) {
                int row = bym * 256 + wr * 64 + mi * 16 + (l >> 4) * 4 + rg;
                Sb[((size_t)row << 12) + col] =
                    (_Float16)(acc[mi][ni][rg] * SCALE);
            }
        }
}

// ---------- kernel 4: per-row exact top-k + softmax -> dense fp16 P row ----------
// r11 showed VALUBusy 73-77% (VALU-issue-bound). NEW: (a) keys held as u32
// (key16 in low bits) — kills 16-bit-op legalization (zext/mask per use);
// uint4 load + shift/mask extraction; (b) compaction via wave-scan +
// block-offset slots (deterministic thread-order) — removes the nc-长
// serialized single-address atomicAdd chain. Selected set, tie-break, and
// P bit-identical (candidate order was value-irrelevant; now deterministic).
__global__ __launch_bounds__(256) void select_scatter(
        const _Float16* __restrict__ S, _Float16* __restrict__ P) {
    __shared__ unsigned hist[256];
    __shared__ unsigned scan[256];
    __shared__ unsigned candKey[NN];     // worst case: all in one bin
    __shared__ unsigned wred[4];
    __shared__ float    wsum[4];
    __shared__ unsigned sh_d, sh_cntgt, sh_T;
    __shared__ int      sh_need;

    const int t = threadIdx.x;
    const int l = t & 63;
    const int w = t >> 6;

    // per-wave level-1 histograms alias candKey[0..1023] (dead until compaction)
    unsigned (*hist4)[256] = (unsigned (*)[256])candKey;

    float    val[16];
    unsigned ukey[16];    // key16 zero-extended to u32 (all math 32-bit)
    {
        const uint4* Srow = (const uint4*)
            ((const unsigned short*)(S + ((size_t)blockIdx.x << 12)) + t * 16);
        uint4 d0 = Srow[0];
        uint4 d1 = Srow[1];
        unsigned wb[8] = {d0.x, d0.y, d0.z, d0.w, d1.x, d1.y, d1.z, d1.w};
#pragma unroll
        for (int p = 0; p < 8; p++) {
            unsigned lo = wb[p] & 0xFFFFu;
            unsigned hi = wb[p] >> 16;
            ukey[2 * p]     = lo ^ ((lo & 0x8000u) ? 0xFFFFu : 0x8000u);
            ukey[2 * p + 1] = hi ^ ((hi & 0x8000u) ? 0xFFFFu : 0x8000u);
            unsigned short ls = (unsigned short)lo, hs = (unsigned short)hi;
            _Float16 lh, hh;
            __builtin_memcpy(&lh, &ls, 2);
            __builtin_memcpy(&hh, &hs, 2);
            val[2 * p]     = (float)lh;
            val[2 * p + 1] = (float)hh;
        }
    }

#pragma unroll
    for (int w2 = 0; w2 < 4; w2++) hist4[w2][t] = 0u;
    __syncthreads();

    // ---- level 1: per-wave histograms on key16 top byte ----
#pragma unroll
    for (int j = 0; j < 16; j++) atomicAdd(&hist4[w][ukey[j] >> 8], 1u);
    __syncthreads();
    // merge (same-thread write->read into find_digit, no extra sync needed)
    hist[t] = hist4[0][t] + hist4[1][t] + hist4[2][t] + hist4[3][t];

    int rem = KK;

    auto find_digit = [&](int remv) {
        unsigned v = hist[t];
#pragma unroll
        for (int off = 1; off < 64; off <<= 1) {
            unsigned o = __shfl_down(v, off);
            if (l + off < 64) v += o;
        }
        if (l == 0) wred[w] = v;
        __syncthreads();
        unsigned add = 0u;
#pragma unroll
        for (int w2 = 0; w2 < 4; w2++) if (w2 > w) add += wred[w2];
        scan[t] = v + add;
        __syncthreads();
        unsigned sufd  = scan[t];
        unsigned sufd1 = (t < 255) ? scan[t + 1] : 0u;
        if (sufd >= (unsigned)remv && sufd1 < (unsigned)remv) {
            sh_d = (unsigned)t; sh_cntgt = sufd1;
        }
        __syncthreads();
    };

    find_digit(rem);
    const unsigned dbin = sh_d;
    rem -= (int)sh_cntgt;

    // ---- compaction via wave-scan (no serialized atomics) ----
    int cnt = 0;
#pragma unroll
    for (int j = 0; j < 16; j++) if ((ukey[j] >> 8) == dbin) cnt++;
    int pre = cnt;
#pragma unroll
    for (int off = 1; off < 64; off <<= 1) {
        int o = __shfl_up(pre, off);
        if (l >= off) pre += o;
    }
    if (l == 63) wred[w] = (unsigned)pre;    // wave totals
    __syncthreads();
    int base = 0;
#pragma unroll
    for (int w2 = 0; w2 < 4; w2++) if (w2 < w) base += (int)wred[w2];
    const int nc = (int)(wred[0] + wred[1] + wred[2] + wred[3]);
    int slot = base + pre - cnt;             // global exclusive prefix
#pragma unroll
    for (int j = 0; j < 16; j++)
        if ((ukey[j] >> 8) == dbin) candKey[slot++] = ukey[j];
    __syncthreads();

    // ---- level 2: exact rem-th largest among candidates ----
    if (nc <= 256) {
        // parallel per-candidate rank: thread i owns candidate i
        if (t < nc) {
            const unsigned ki = candKey[t];
            int g = 0, m = 0;
            for (int j = 0; j < nc; j++) {
                unsigned kj = candKey[j];      // LDS broadcast (no conflict)
                g += (kj > ki) ? 1 : 0;
                m += (kj == ki) ? 1 : 0;
            }
            if (g < rem && g + m >= rem) {     // value-determined: benign race
                sh_T = ki; sh_need = rem - g;
            }
        }
    } else {
        // all candidates share top byte: ONE histogram pass on the low byte
        hist[t] = 0u;
        __syncthreads();
        for (int i = t; i < nc; i += 256)
            atomicAdd(&hist[candKey[i] & 255u], 1u);
        __syncthreads();
        find_digit(rem);
        if (t == 0) { sh_T = (dbin << 8) | sh_d; sh_need = rem - (int)sh_cntgt; }
    }
    __syncthreads();
    const unsigned Tk = sh_T;                  // key16 in low bits
    const int need = sh_need;
    float mT;
    {
        unsigned tu = (Tk & 0x8000u) ? (Tk ^ 0x8000u) : (~Tk & 0xFFFFu);
        unsigned short ts = (unsigned short)tu;
        _Float16 th;
        __builtin_memcpy(&th, &ts, 2);
        mT = (float)th;   // softmax shift: shift-invariant, any m works
    }

    // stable tie-break: exclusive prefix of per-thread equal counts (wave scan)
    int eqc = 0;
#pragma unroll
    for (int j = 0; j < 16; j++) if (ukey[j] == Tk) eqc++;
    int vinc = eqc;
#pragma unroll
    for (int off = 1; off < 64; off <<= 1) {
        int o = __shfl_up(vinc, off);
        if (l >= off) vinc += o;
    }
    if (l == 63) wred[w] = (unsigned)vinc;
    __syncthreads();
    int addlow = 0;
#pragma unroll
    for (int w2 = 0; w2 < 4; w2++) if (w2 < w) addlow += (int)wred[w2];
    const int eqexcl = vinc - eqc + addlow;

    // selection + exp: key>Tk unconditional, ties = exp(0) = 1.0f exactly
    float pv[16];
    float le = 0.f;
#pragma unroll
    for (int j = 0; j < 16; j++) {
        float e = 0.f;
        if (ukey[j] > Tk) { e = __expf(val[j] - mT); le += e; }
        pv[j] = e;
    }
    if (eqc) {
        int seen = 0;
#pragma unroll
        for (int j = 0; j < 16; j++) {
            if (ukey[j] == Tk) {
                if (eqexcl + seen < need) { pv[j] = 1.0f; le += 1.0f; }
                seen++;
            }
        }
    }

    // sum reduce
#pragma unroll
    for (int off = 32; off > 0; off >>= 1) {
        float o = __shfl_down(le, off);
        if (l + off < 64) le += o;
    }
    if (l == 0) wsum[w] = le;
    __syncthreads();
    const float inv = 1.0f / (wsum[0] + wsum[1] + wsum[2] + wsum[3]);

    half8 ra, rb;
#pragma unroll
    for (int j = 0; j < 8; j++) {
        ra[j] = (_Float16)(pv[j] * inv);
        rb[j] = (_Float16)(pv[j + 8] * inv);
    }
    _Float16* Pr = P + (size_t)blockIdx.x * PSTRIDE + t * 16;
    *(half8*)Pr       = ra;
    *(half8*)(Pr + 8) = rb;
}

// ---------- kernel 5: out[b][c][n] = sum_m Vt[c][m] * P[n][m] via MFMA f16 ----------
// NEW: r11-score-proven counted-vmcnt double-buffer. BK=256 tiles (4 chunks),
// 128 KB LDS (1 blk/CU; 512 blocks = 2 rounds). Stage next tile's 16 loads
// FIRST, vmcnt(16) retires only the current tile's 16, next-tile loads fly
// under the 32-MFMA compute. MFMA order identical to r9 -> bit-identical out.
__global__ __launch_bounds__(256) void av_gemm(
        const _Float16* __restrict__ Vt, const _Float16* __restrict__ P,
        float* __restrict__ out) {
    __shared__ _Float16 As[2][4][64][64];   // 64 KB
    __shared__ _Float16 Bs[2][4][64][64];   // 64 KB

    const int t    = threadIdx.x;
    const int wave = t >> 6;
    const int l    = t & 63;
    const int wr   = wave >> 1;
    const int wc   = wave & 1;
    const int bxn  = blockIdx.x;
    const int byc  = blockIdx.y;
    const int b    = blockIdx.z;

    const int lr = l >> 3;
    const int gg = (l & 7) ^ lr;

    const _Float16* At = Vt + ((size_t)((b << 8) + byc * 64)) * NN;
    const _Float16* Bt = P + ((size_t)(b * NN + bxn * 64)) * PSTRIDE;
    const size_t lane_offA = (size_t)lr * NN + gg * 8;
    const size_t lane_offB = (size_t)lr * PSTRIDE + gg * 8;

    floatx4 acc[2][2];
#pragma unroll
    for (int i = 0; i < 2; i++)
#pragma unroll
        for (int j = 0; j < 2; j++) acc[i][j] = (floatx4)0.0f;

    const int rowA   = l & 15;
    const int sgbase = (l >> 4) ^ (l & 7);

    // prologue: issue tile 0's 16 loads (no wait)
#pragma unroll
    for (int c = 0; c < 4; c++)
#pragma unroll
        for (int s = 0; s < 2; s++) {
            const int seg = wave * 2 + s;
            gload16(At + (size_t)seg * 8 * NN + lane_offA + c * 64,
                    &As[0][c][seg * 8][0]);
            gload16(Bt + (size_t)seg * 8 * PSTRIDE + lane_offB + c * 64,
                    &Bs[0][c][seg * 8][0]);
        }

    for (int kt = 0; kt < 16; ++kt) {
        const int cur = kt & 1;
        if (kt < 15) {
            const int kc = (kt + 1) * 256;
#pragma unroll
            for (int c = 0; c < 4; c++)
#pragma unroll
                for (int s = 0; s < 2; s++) {
                    const int seg = wave * 2 + s;
                    gload16(At + (size_t)seg * 8 * NN + lane_offA + kc + c * 64,
                            &As[cur ^ 1][c][seg * 8][0]);
                    gload16(Bt + (size_t)seg * 8 * PSTRIDE + lane_offB + kc + c * 64,
                            &Bs[cur ^ 1][c][seg * 8][0]);
                }
            // outstanding = 16 (tile kt) + 16 (tile kt+1); retire oldest 16
            asm volatile("s_waitcnt vmcnt(16)" ::: "memory");
        } else {
            asm volatile("s_waitcnt vmcnt(0)" ::: "memory");
        }
        __builtin_amdgcn_s_barrier();
        asm volatile("" ::: "memory");

#pragma unroll
        for (int c = 0; c < 4; c++)
#pragma unroll
            for (int st = 0; st < 2; st++) {
                const int sg = sgbase ^ (st ? 4 : 0);
                half8 af[2], bf[2];
#pragma unroll
                for (int mi = 0; mi < 2; mi++)
                    af[mi] = *(const half8*)&As[cur][c][wr * 32 + mi * 16 + rowA][sg * 8];
#pragma unroll
                for (int ni = 0; ni < 2; ni++)
                    bf[ni] = *(const half8*)&Bs[cur][c][wc * 32 + ni * 16 + rowA][sg * 8];
#pragma unroll
                for (int mi = 0; mi < 2; mi++)
#pragma unroll
                    for (int ni = 0; ni < 2; ni++)
                        acc[mi][ni] = __builtin_amdgcn_mfma_f32_16x16x32_f16(
                            af[mi], bf[ni], acc[mi][ni], 0, 0, 0);
            }
        __builtin_amdgcn_s_barrier();
        asm volatile("" ::: "memory");
    }

#pragma unroll
    for (int mi = 0; mi < 2; mi++)
#pragma unroll
        for (int ni = 0; ni < 2; ni++) {
            int col = bxn * 64 + wc * 32 + ni * 16 + (l & 15);
#pragma unroll
            for (int rg = 0; rg < 4; rg++) {
                int row = byc * 64 + wr * 32 + mi * 16 + (l >> 4) * 4 + rg;
                out[((size_t)((b << 8) + row) << 12) + col] = acc[mi][ni][rg];
            }
        }
}

extern "C" void kernel_launch(void* const* d_in, const int* in_sizes, int n_in,
                              void* d_out, int out_size, void* d_ws, size_t ws_size,
                              hipStream_t stream) {
    const float* x  = (const float*)d_in[0];
    const float* Wq = (const float*)d_in[1];
    const float* bq = (const float*)d_in[2];
    const float* Wk = (const float*)d_in[3];
    const float* bk = (const float*)d_in[4];
    const float* Wv = (const float*)d_in[5];
    const float* bv = (const float*)d_in[6];
    float* out = (float*)d_out;

    char* ws = (char*)d_ws;
    _Float16* Wcat = (_Float16*)ws;                            // 1.18 MB
    _Float16* Qcat = (_Float16*)(ws + 1179648);                // 12.6 MB
    _Float16* Kcat = (_Float16*)(ws + 1179648 + 12582912);     // 12.6 MB
    _Float16* Vt   = (_Float16*)(ws + 1179648 + 2 * 12582912); // 4 MB
    _Float16* S    = (_Float16*)(ws + 1179648 + 2 * 12582912 + 4194304); // 64 MB fp16
    _Float16* xcat = (_Float16*)S;   // xcat dead before score_gemm writes S
    _Float16* P    = (_Float16*)S;   // P row aliases fp16 S row exactly (8 KB)

    xpose_wcat_kernel<<<dim3(64, 5, BATCH), 256, 0, stream>>>(x, Wq, Wk, Wv,
                                                              xcat, Wcat);
    proj_gemm<<<dim3(128, 1, 3), 256, 0, stream>>>(xcat, Wcat, bq, bk, bv,
                                                   Qcat, Kcat, Vt);
    score_gemm<<<dim3(512, 1, 1), 512, 0, stream>>>(Qcat, Kcat, S);
    select_scatter<<<BATCH * NN, 256, 0, stream>>>(S, P);
    av_gemm<<<dim3(64, 4, BATCH), 256, 0, stream>>>(Vt, P, out);
}

// Round 13
// 242.656 us; speedup vs baseline: 1.0372x; 1.0372x over previous
//
#include <hip/hip_runtime.h>
#include <hip/hip_bf16.h>
#include <math.h>

#define BATCH 2
#define CC    256
#define NN    4096
#define KK    409          // max(1, int(0.1*4096))
#define KCAT  768          // split-fp16 concat K (compensated product — REQUIRED,
                           // r5 showed dropping it fails tolerance: 0.0127 > 0.0117)
#define SCALE 0.0625f      // 1/sqrt(256)
#define PSTRIDE 4096       // P row stride in halfs (P row aliases fp16 S row exactly)

typedef _Float16 half8 __attribute__((ext_vector_type(8)));
typedef float    floatx4 __attribute__((ext_vector_type(4)));

// async global->LDS, 16B per lane; LDS dest = wave-uniform base + lane*16
typedef __attribute__((address_space(3))) unsigned       lds_u32;
typedef __attribute__((address_space(1))) const unsigned glb_u32;
__device__ __forceinline__ void gload16(const void* g, void* l) {
    __builtin_amdgcn_global_load_lds((glb_u32*)g, (lds_u32*)l, 16, 0, 0);
}

// decode key16 (low 16 bits) back to the fp16 value, as float
__device__ __forceinline__ float keyval(unsigned k) {
    unsigned tops = (k >> 15) & 1u;
    unsigned u = k ^ (0x8000u | ((1u - tops) * 0x7FFFu));
    unsigned short us = (unsigned short)u;
    _Float16 h; __builtin_memcpy(&h, &us, 2);
    return (float)h;
}

// ---------- kernel 1: xpose (by<4) + wcat (by==4) merged ----------
__global__ __launch_bounds__(256) void xpose_wcat_kernel(
        const float* __restrict__ x,
        const float* __restrict__ Wq, const float* __restrict__ Wk,
        const float* __restrict__ Wv,
        _Float16* __restrict__ xcat, _Float16* __restrict__ Wcat) {
    const int t  = threadIdx.x;
    if (blockIdx.y == 4) {
        int idx = (blockIdx.z * 64 + blockIdx.x) * 256 + t;
#pragma unroll
        for (int k = 0; k < 6; k++) {
            int e = idx + k * 32768;              // covers 3*65536 exactly
            int mat = e >> 16;
            int o   = (e >> 8) & 255;
            int c   = e & 255;
            const float* W = (mat == 0) ? Wq : (mat == 1) ? Wk : Wv;
            float v = W[o * 256 + c];
            _Float16 hi = (_Float16)v;
            _Float16 lo = (_Float16)(v - (float)hi);
            _Float16* wr = Wcat + ((size_t)(mat * 256 + o)) * KCAT;
            wr[c] = hi; wr[256 + c] = hi; wr[512 + c] = lo;
        }
        return;
    }

    __shared__ float xs[64][68];
    const int n0 = blockIdx.x * 64;
    const int c0 = blockIdx.y * 64;
    const int b  = blockIdx.z;

    {
        const int ci = t >> 2;
        const int j  = (t & 3) * 16;
        const float* xp = x + ((size_t)((b << 8) + c0 + ci)) * NN + n0 + j;
        float4 a0 = ((const float4*)xp)[0];
        float4 a1 = ((const float4*)xp)[1];
        float4 a2 = ((const float4*)xp)[2];
        float4 a3 = ((const float4*)xp)[3];
        *(float4*)&xs[ci][j]      = a0;
        *(float4*)&xs[ci][j + 4]  = a1;
        *(float4*)&xs[ci][j + 8]  = a2;
        *(float4*)&xs[ci][j + 12] = a3;
    }
    __syncthreads();

    const int n = t >> 2;
    const int g0 = t & 3;
    _Float16* xr = xcat + ((size_t)(b * NN + n0 + n)) * KCAT + c0;
#pragma unroll
    for (int gg = 0; gg < 2; gg++) {
        int g = g0 + gg * 4;
        half8 hi, lo;
#pragma unroll
        for (int k = 0; k < 8; k++) {
            float v = xs[g * 8 + k][n];
            _Float16 h = (_Float16)v;
            hi[k] = h;
            lo[k] = (_Float16)(v - (float)h);
        }
        *(half8*)(xr + g * 8)       = hi;
        *(half8*)(xr + 256 + g * 8) = lo;
        *(half8*)(xr + 512 + g * 8) = hi;
    }
}

// ---------- kernel 2: projections via MFMA, 128x128 tile, K=768 ----------
// 2-phase double-buffered; compensated split (KCAT=768) throughout. FROZEN.
__global__ __launch_bounds__(256) void proj_gemm(
        const _Float16* __restrict__ xcat, const _Float16* __restrict__ Wcat,
        const float* __restrict__ bq, const float* __restrict__ bk,
        const float* __restrict__ bv,
        _Float16* __restrict__ Qcat, _Float16* __restrict__ Kcat,
        _Float16* __restrict__ Vt) {
    __shared__ _Float16 As[2][128][64];
    __shared__ _Float16 Bs[2][128][64];

    const int t    = threadIdx.x;
    const int wave = t >> 6;
    const int l    = t & 63;
    const int wr   = wave >> 1;
    const int wc   = wave & 1;
    const int mat  = blockIdx.z;

    int bym, bxn;
    if (mat < 2) { bym = blockIdx.x >> 1; bxn = blockIdx.x & 1; }
    else         { bym = blockIdx.x & 1;  bxn = blockIdx.x >> 1; }

    const int lr = l >> 3;
    const int gg = (l & 7) ^ lr;

    const _Float16* At;
    const _Float16* Bt;
    if (mat < 2) {
        At = xcat + ((size_t)(bym * 128)) * KCAT;
        Bt = Wcat + ((size_t)(mat * 256 + bxn * 128)) * KCAT;
    } else {
        At = Wcat + ((size_t)(512 + bym * 128)) * KCAT;
        Bt = xcat + ((size_t)(bxn * 128)) * KCAT;
    }
    const size_t lane_off = (size_t)lr * KCAT + gg * 8;

    floatx4 acc[4][4];
#pragma unroll
    for (int i = 0; i < 4; i++)
#pragma unroll
        for (int j = 0; j < 4; j++) acc[i][j] = (floatx4)0.0f;

    const int rowA = l & 15;
    const int sg0  = (l >> 4) ^ (l & 7);
    const int sg1  = sg0 ^ 4;

    // prologue: stage K-tile 0
#pragma unroll
    for (int s = 0; s < 4; s++) {
        const int seg = wave * 4 + s;
        gload16(At + (size_t)seg * 8 * KCAT + lane_off, &As[0][seg * 8][0]);
        gload16(Bt + (size_t)seg * 8 * KCAT + lane_off, &Bs[0][seg * 8][0]);
    }
    __syncthreads();

    for (int kt = 0; kt < 12; ++kt) {
        const int cur = kt & 1;
        if (kt < 11) {
            const int kc = (kt + 1) * 64;
#pragma unroll
            for (int s = 0; s < 4; s++) {
                const int seg = wave * 4 + s;
                gload16(At + (size_t)seg * 8 * KCAT + lane_off + kc,
                        &As[cur ^ 1][seg * 8][0]);
                gload16(Bt + (size_t)seg * 8 * KCAT + lane_off + kc,
                        &Bs[cur ^ 1][seg * 8][0]);
            }
        }
#pragma unroll
        for (int ks = 0; ks < 2; ks++) {
            const int sg = ks ? sg1 : sg0;
            half8 af[4], bf[4];
#pragma unroll
            for (int mi = 0; mi < 4; mi++)
                af[mi] = *(const half8*)&As[cur][wr * 64 + mi * 16 + rowA][sg * 8];
#pragma unroll
            for (int ni = 0; ni < 4; ni++)
                bf[ni] = *(const half8*)&Bs[cur][wc * 64 + ni * 16 + rowA][sg * 8];
#pragma unroll
            for (int mi = 0; mi < 4; mi++)
#pragma unroll
                for (int ni = 0; ni < 4; ni++)
                    acc[mi][ni] = __builtin_amdgcn_mfma_f32_16x16x32_f16(
                        af[mi], bf[ni], acc[mi][ni], 0, 0, 0);
        }
        __syncthreads();
    }

    if (mat < 2) {
        const float* bias = (mat == 0) ? bq : bk;
        _Float16* Out = (mat == 0) ? Qcat : Kcat;
#pragma unroll
        for (int ni = 0; ni < 4; ni++) {
            int ch = bxn * 128 + wc * 64 + ni * 16 + (l & 15);
            float bb = bias[ch];
#pragma unroll
            for (int mi = 0; mi < 4; mi++)
#pragma unroll
                for (int rg = 0; rg < 4; rg++) {
                    int token = bym * 128 + wr * 64 + mi * 16 + (l >> 4) * 4 + rg;
                    float v = acc[mi][ni][rg] + bb;
                    _Float16 hi = (_Float16)v;
                    _Float16 lo = (_Float16)(v - (float)hi);
                    _Float16* p = Out + (size_t)token * KCAT + ch;
                    if (mat == 0) { p[0] = hi; p[256] = lo; p[512] = hi; }
                    else          { p[0] = hi; p[256] = hi; p[512] = lo; }
                }
        }
    } else {
#pragma unroll
        for (int mi = 0; mi < 4; mi++)
#pragma unroll
            for (int rg = 0; rg < 4; rg++) {
                int ch = bym * 128 + wr * 64 + mi * 16 + (l >> 4) * 4 + rg;
                float bb = bv[ch];
#pragma unroll
                for (int ni = 0; ni < 4; ni++) {
                    int col = bxn * 128 + wc * 64 + ni * 16 + (l & 15);
                    int b = col >> 12, n = col & 4095;
                    Vt[((size_t)((b << 8) + ch)) * NN + n] =
                        (_Float16)(acc[mi][ni][rg] + bb);
                }
            }
    }
}

// ---------- kernel 3: S = (Qcat @ Kcat^T) * SCALE via MFMA f16, fp16 S ----------
// r11-proven counted-vmcnt 2-phase: BK=64 double-buffer (128 KB LDS, 512 thr
// keeps 2 waves/SIMD), stage-next FIRST, vmcnt(8). FROZEN.
__global__ __launch_bounds__(512, 2) void score_gemm(
        const _Float16* __restrict__ Qcat, const _Float16* __restrict__ Kcat,
        _Float16* __restrict__ S) {
    __shared__ _Float16 As[2][256][64];   // 64 KB
    __shared__ _Float16 Bs[2][256][64];   // 64 KB

    const int t    = threadIdx.x;
    const int wave = t >> 6;             // 0..7
    const int l    = t & 63;
    const int wr   = wave >> 1;          // 0..3 (M)
    const int wc   = wave & 1;           // 0..1 (N)

    const int id  = blockIdx.x;
    const int sc  = id & 7;              // supercell == XCD (id%8 round-robin)
    const int j   = id >> 3;             // 0..63 within supercell
    const int b   = sc & 1;
    const int scq = sc >> 1;             // quadrant 0..3
    const int bxn = ((scq & 1) << 3) + (j & 7);
    const int bym = ((scq >> 1) << 3) + (j >> 3);

    const int lr = l >> 3;
    const int gg = (l & 7) ^ lr;

    const _Float16* At = Qcat + ((size_t)((b << 12) + bym * 256)) * KCAT;
    const _Float16* Bt = Kcat + ((size_t)((b << 12) + bxn * 256)) * KCAT;
    const size_t lane_off = (size_t)lr * KCAT + gg * 8;

    floatx4 acc[4][8];
#pragma unroll
    for (int i = 0; i < 4; i++)
#pragma unroll
        for (int jj = 0; jj < 8; jj++) acc[i][jj] = (floatx4)0.0f;

    const int rowA = l & 15;
    const int sg0  = (l >> 4) ^ (l & 7);
    const int sg1  = sg0 ^ 4;

    // prologue: issue K-tile 0 loads into buffer 0 (no wait here)
#pragma unroll
    for (int s = 0; s < 4; s++) {
        const int seg = wave * 4 + s;
        gload16(At + (size_t)seg * 8 * KCAT + lane_off, &As[0][seg * 8][0]);
        gload16(Bt + (size_t)seg * 8 * KCAT + lane_off, &Bs[0][seg * 8][0]);
    }

    for (int kt = 0; kt < 12; ++kt) {
        const int cur = kt & 1;
        // stage tile kt+1 into the other buffer (8 gload16 / thread)
        if (kt < 11) {
            const int kc = (kt + 1) * 64;
#pragma unroll
            for (int s = 0; s < 4; s++) {
                const int seg = wave * 4 + s;
                gload16(At + (size_t)seg * 8 * KCAT + lane_off + kc,
                        &As[cur ^ 1][seg * 8][0]);
                gload16(Bt + (size_t)seg * 8 * KCAT + lane_off + kc,
                        &Bs[cur ^ 1][seg * 8][0]);
            }
            // outstanding = 8 (tile kt) + 8 (tile kt+1); retire the oldest 8
            asm volatile("s_waitcnt vmcnt(8)" ::: "memory");
        } else {
            asm volatile("s_waitcnt vmcnt(0)" ::: "memory");
        }
        __builtin_amdgcn_s_barrier();          // all waves' tile-kt segs ready
        asm volatile("" ::: "memory");

#pragma unroll
        for (int ks = 0; ks < 2; ks++) {
            const int sg = ks ? sg1 : sg0;
            half8 af[4], bf[8];
#pragma unroll
            for (int mi = 0; mi < 4; mi++)
                af[mi] = *(const half8*)&As[cur][wr * 64 + mi * 16 + rowA][sg * 8];
#pragma unroll
            for (int ni = 0; ni < 8; ni++)
                bf[ni] = *(const half8*)&Bs[cur][wc * 128 + ni * 16 + rowA][sg * 8];
#pragma unroll
            for (int mi = 0; mi < 4; mi++)
#pragma unroll
                for (int ni = 0; ni < 8; ni++)
                    acc[mi][ni] = __builtin_amdgcn_mfma_f32_16x16x32_f16(
                        af[mi], bf[ni], acc[mi][ni], 0, 0, 0);
        }
        __builtin_amdgcn_s_barrier();          // reads of buf[cur] done before
        asm volatile("" ::: "memory");         // next iter overwrites it
    }

    _Float16* Sb = S + ((size_t)b << 24);   // NN*NN halfs per batch
#pragma unroll
    for (int mi = 0; mi < 4; mi++)
#pragma unroll
        for (int ni = 0; ni < 8; ni++) {
            int col = bxn * 256 + wc * 128 + ni * 16 + (l & 15);
#pragma unroll
            for (int rg = 0; rg < 4; rg++) {
                int row = bym * 256 + wr * 64 + mi * 16 + (l >> 4) * 4 + rg;
                Sb[((size_t)row << 12) + col] =
                    (_Float16)(acc[mi][ni][rg] * SCALE);
            }
        }
}

// ---------- kernel 4: per-row exact top-k + softmax -> dense fp16 P row ----------
// NEW (packed-key16 rewrite): persistent per-thread state = kp[8] ONLY
// (two key16 per u32, 3-op packed branchless transform). val/pv arrays
// deleted — values decoded from keys on use, exp recomputed in the write
// pass (deterministic -> bit-identical). Removes spill/rematerialization
// risk (r12 VGPR_Count=32 vs 48+ live array elements) and halves key-
// extraction VALU. Selection set, tie-break order, summation order exact.
__global__ __launch_bounds__(256) void select_scatter(
        const _Float16* __restrict__ S, _Float16* __restrict__ P) {
    __shared__ unsigned hist[256];
    __shared__ unsigned scan[256];
    __shared__ unsigned candKey[NN];     // worst case: all in one bin
    __shared__ unsigned wred[4];
    __shared__ float    wsum[4];
    __shared__ unsigned sh_d, sh_cntgt, sh_T;
    __shared__ int      sh_need;

    const int t = threadIdx.x;
    const int l = t & 63;
    const int w = t >> 6;

    // per-wave level-1 histograms alias candKey[0..1023] (dead until compaction)
    unsigned (*hist4)[256] = (unsigned (*)[256])candKey;

    unsigned kp[8];   // packed key16 pairs — the ONLY persistent array
    {
        const uint4* Srow = (const uint4*)
            ((const unsigned short*)(S + ((size_t)blockIdx.x << 12)) + t * 16);
        uint4 d0 = Srow[0];
        uint4 d1 = Srow[1];
        unsigned wb[8] = {d0.x, d0.y, d0.z, d0.w, d1.x, d1.y, d1.z, d1.w};
#pragma unroll
        for (int p = 0; p < 8; p++) {
            unsigned tops = (wb[p] >> 15) & 0x10001u;
            kp[p] = wb[p] ^ ((tops * 0xFFFFu) | 0x80008000u);
        }
    }
    // element j (global col = t*16 + j): low half = even j, high half = odd j
    auto KEY = [&](int j) -> unsigned {
        return (j & 1) ? (kp[j >> 1] >> 16) : (kp[j >> 1] & 0xFFFFu);
    };

#pragma unroll
    for (int w2 = 0; w2 < 4; w2++) hist4[w2][t] = 0u;
    __syncthreads();

    // ---- level 1: per-wave histograms on key16 top byte (packed) ----
#pragma unroll
    for (int p = 0; p < 8; p++) {
        atomicAdd(&hist4[w][(kp[p] >> 8) & 255u], 1u);
        atomicAdd(&hist4[w][kp[p] >> 24], 1u);
    }
    __syncthreads();
    // merge (same-thread write->read into find_digit, no extra sync needed)
    hist[t] = hist4[0][t] + hist4[1][t] + hist4[2][t] + hist4[3][t];

    int rem = KK;

    auto find_digit = [&](int remv) {
        unsigned v = hist[t];
#pragma unroll
        for (int off = 1; off < 64; off <<= 1) {
            unsigned o = __shfl_down(v, off);
            if (l + off < 64) v += o;
        }
        if (l == 0) wred[w] = v;
        __syncthreads();
        unsigned add = 0u;
#pragma unroll
        for (int w2 = 0; w2 < 4; w2++) if (w2 > w) add += wred[w2];
        scan[t] = v + add;
        __syncthreads();
        unsigned sufd  = scan[t];
        unsigned sufd1 = (t < 255) ? scan[t + 1] : 0u;
        if (sufd >= (unsigned)remv && sufd1 < (unsigned)remv) {
            sh_d = (unsigned)t; sh_cntgt = sufd1;
        }
        __syncthreads();
    };

    find_digit(rem);
    const unsigned dbin = sh_d;
    rem -= (int)sh_cntgt;

    // ---- compaction via wave-scan (no serialized atomics) ----
    int cnt = 0;
#pragma unroll
    for (int j = 0; j < 16; j++) if ((KEY(j) >> 8) == dbin) cnt++;
    int pre = cnt;
#pragma unroll
    for (int off = 1; off < 64; off <<= 1) {
        int o = __shfl_up(pre, off);
        if (l >= off) pre += o;
    }
    if (l == 63) wred[w] = (unsigned)pre;    // wave totals
    __syncthreads();
    int base = 0;
#pragma unroll
    for (int w2 = 0; w2 < 4; w2++) if (w2 < w) base += (int)wred[w2];
    const int nc = (int)(wred[0] + wred[1] + wred[2] + wred[3]);
    int slot = base + pre - cnt;             // global exclusive prefix
#pragma unroll
    for (int j = 0; j < 16; j++) {
        unsigned k = KEY(j);
        if ((k >> 8) == dbin) candKey[slot++] = k;
    }
    __syncthreads();

    // ---- level 2: exact rem-th largest among candidates ----
    if (nc <= 256) {
        // parallel per-candidate rank: thread i owns candidate i
        if (t < nc) {
            const unsigned ki = candKey[t];
            int g = 0, m = 0;
            for (int j = 0; j < nc; j++) {
                unsigned kj = candKey[j];      // LDS broadcast (no conflict)
                g += (kj > ki) ? 1 : 0;
                m += (kj == ki) ? 1 : 0;
            }
            if (g < rem && g + m >= rem) {     // value-determined: benign race
                sh_T = ki; sh_need = rem - g;
            }
        }
    } else {
        // all candidates share top byte: ONE histogram pass on the low byte
        hist[t] = 0u;
        __syncthreads();
        for (int i = t; i < nc; i += 256)
            atomicAdd(&hist[candKey[i] & 255u], 1u);
        __syncthreads();
        find_digit(rem);
        if (t == 0) { sh_T = (dbin << 8) | sh_d; sh_need = rem - (int)sh_cntgt; }
    }
    __syncthreads();
    const unsigned Tk = sh_T;                  // key16 in low bits
    const int need = sh_need;
    const float mT = keyval(Tk);   // softmax shift: shift-invariant, any m works

    // stable tie-break: exclusive prefix of per-thread equal counts (wave scan)
    int eqc = 0;
#pragma unroll
    for (int j = 0; j < 16; j++) if (KEY(j) == Tk) eqc++;
    int vinc = eqc;
#pragma unroll
    for (int off = 1; off < 64; off <<= 1) {
        int o = __shfl_up(vinc, off);
        if (l >= off) vinc += o;
    }
    if (l == 63) wred[w] = (unsigned)vinc;
    __syncthreads();
    int addlow = 0;
#pragma unroll
    for (int w2 = 0; w2 < 4; w2++) if (w2 < w) addlow += (int)wred[w2];
    const int eqexcl = vinc - eqc + addlow;

    // pass 1 — denominator: exps in j-order, then ties as repeated +1.0
    // (identical summation order to the pv[]-array version)
    float le = 0.f;
#pragma unroll
    for (int j = 0; j < 16; j++) {
        unsigned k = KEY(j);
        if (k > Tk) le += __expf(keyval(k) - mT);
    }
    {
        int nsel = need - eqexcl;
        if (nsel < 0) nsel = 0;
        if (nsel > eqc) nsel = eqc;
        for (int i = 0; i < nsel; i++) le += 1.0f;
    }

    // sum reduce
#pragma unroll
    for (int off = 32; off > 0; off >>= 1) {
        float o = __shfl_down(le, off);
        if (l + off < 64) le += o;
    }
    if (l == 0) wsum[w] = le;
    __syncthreads();
    const float inv = 1.0f / (wsum[0] + wsum[1] + wsum[2] + wsum[3]);

    // pass 2 — recompute exp (bit-identical) and write normalized P
    half8 ra, rb;
    {
        int seen = 0;
#pragma unroll
        for (int j = 0; j < 16; j++) {
            unsigned k = KEY(j);
            float e = 0.f;
            if (k > Tk) {
                e = __expf(keyval(k) - mT) * inv;
            } else if (k == Tk) {
                if (eqexcl + seen < need) e = inv;   // pv=1.0 -> 1.0*inv
                seen++;
            }
            if (j < 8) ra[j] = (_Float16)e;
            else       rb[j - 8] = (_Float16)e;
        }
    }
    _Float16* Pr = P + (size_t)blockIdx.x * PSTRIDE + t * 16;
    *(half8*)Pr       = ra;
    *(half8*)(Pr + 8) = rb;
}

// ---------- kernel 5: out[b][c][n] = sum_m Vt[c][m] * P[n][m] via MFMA f16 ----------
// REVERTED to r9-proven: BK=256 single-buffered (4 x 64x64 K-chunks, 64 KB
// LDS, 2 blocks/CU = 2 waves/SIMD). r12's counted-vmcnt dbuf at 128 KB fell
// to 1 wave/SIMD and regressed ~15 µs — counted-vmcnt only pays when >=2
// waves/SIMD survive the LDS doubling (score has 512 thr; av has 256).
__global__ __launch_bounds__(256) void av_gemm(
        const _Float16* __restrict__ Vt, const _Float16* __restrict__ P,
        float* __restrict__ out) {
    __shared__ _Float16 As[4][64][64];
    __shared__ _Float16 Bs[4][64][64];

    const int t    = threadIdx.x;
    const int wave = t >> 6;
    const int l    = t & 63;
    const int wr   = wave >> 1;
    const int wc   = wave & 1;
    const int bxn  = blockIdx.x;
    const int byc  = blockIdx.y;
    const int b    = blockIdx.z;

    const int lr = l >> 3;
    const int gg = (l & 7) ^ lr;

    const _Float16* At = Vt + ((size_t)((b << 8) + byc * 64)) * NN;
    const _Float16* Bt = P + ((size_t)(b * NN + bxn * 64)) * PSTRIDE;
    const size_t lane_offA = (size_t)lr * NN + gg * 8;
    const size_t lane_offB = (size_t)lr * PSTRIDE + gg * 8;

    floatx4 acc[2][2];
#pragma unroll
    for (int i = 0; i < 2; i++)
#pragma unroll
        for (int j = 0; j < 2; j++) acc[i][j] = (floatx4)0.0f;

    const int rowA   = l & 15;
    const int sgbase = (l >> 4) ^ (l & 7);

    for (int kt = 0; kt < 16; ++kt) {
        const int kc = kt * 256;
#pragma unroll
        for (int c = 0; c < 4; c++)
#pragma unroll
            for (int s = 0; s < 2; s++) {
                const int seg = wave * 2 + s;
                gload16(At + (size_t)seg * 8 * NN + lane_offA + kc + c * 64,
                        &As[c][seg * 8][0]);
                gload16(Bt + (size_t)seg * 8 * PSTRIDE + lane_offB + kc + c * 64,
                        &Bs[c][seg * 8][0]);
            }
        __syncthreads();
#pragma unroll
        for (int c = 0; c < 4; c++)
#pragma unroll
            for (int st = 0; st < 2; st++) {
                const int sg = sgbase ^ (st ? 4 : 0);
                half8 af[2], bf[2];
#pragma unroll
                for (int mi = 0; mi < 2; mi++)
                    af[mi] = *(const half8*)&As[c][wr * 32 + mi * 16 + rowA][sg * 8];
#pragma unroll
                for (int ni = 0; ni < 2; ni++)
                    bf[ni] = *(const half8*)&Bs[c][wc * 32 + ni * 16 + rowA][sg * 8];
#pragma unroll
                for (int mi = 0; mi < 2; mi++)
#pragma unroll
                    for (int ni = 0; ni < 2; ni++)
                        acc[mi][ni] = __builtin_amdgcn_mfma_f32_16x16x32_f16(
                            af[mi], bf[ni], acc[mi][ni], 0, 0, 0);
            }
        __syncthreads();
    }

#pragma unroll
    for (int mi = 0; mi < 2; mi++)
#pragma unroll
        for (int ni = 0; ni < 2; ni++) {
            int col = bxn * 64 + wc * 32 + ni * 16 + (l & 15);
#pragma unroll
            for (int rg = 0; rg < 4; rg++) {
                int row = byc * 64 + wr * 32 + mi * 16 + (l >> 4) * 4 + rg;
                out[((size_t)((b << 8) + row) << 12) + col] = acc[mi][ni][rg];
            }
        }
}

extern "C" void kernel_launch(void* const* d_in, const int* in_sizes, int n_in,
                              void* d_out, int out_size, void* d_ws, size_t ws_size,
                              hipStream_t stream) {
    const float* x  = (const float*)d_in[0];
    const float* Wq = (const float*)d_in[1];
    const float* bq = (const float*)d_in[2];
    const float* Wk = (const float*)d_in[3];
    const float* bk = (const float*)d_in[4];
    const float* Wv = (const float*)d_in[5];
    const float* bv = (const float*)d_in[6];
    float* out = (float*)d_out;

    char* ws = (char*)d_ws;
    _Float16* Wcat = (_Float16*)ws;                            // 1.18 MB
    _Float16* Qcat = (_Float16*)(ws + 1179648);                // 12.6 MB
    _Float16* Kcat = (_Float16*)(ws + 1179648 + 12582912);     // 12.6 MB
    _Float16* Vt   = (_Float16*)(ws + 1179648 + 2 * 12582912); // 4 MB
    _Float16* S    = (_Float16*)(ws + 1179648 + 2 * 12582912 + 4194304); // 64 MB fp16
    _Float16* xcat = (_Float16*)S;   // xcat dead before score_gemm writes S
    _Float16* P    = (_Float16*)S;   // P row aliases fp16 S row exactly (8 KB)

    xpose_wcat_kernel<<<dim3(64, 5, BATCH), 256, 0, stream>>>(x, Wq, Wk, Wv,
                                                              xcat, Wcat);
    proj_gemm<<<dim3(128, 1, 3), 256, 0, stream>>>(xcat, Wcat, bq, bk, bv,
                                                   Qcat, Kcat, Vt);
    score_gemm<<<dim3(512, 1, 1), 512, 0, stream>>>(Qcat, Kcat, S);
    select_scatter<<<BATCH * NN, 256, 0, stream>>>(S, P);
    av_gemm<<<dim3(64, 4, BATCH), 256, 0, stream>>>(Vt, P, out);
}

// Round 14
// 232.270 us; speedup vs baseline: 1.0836x; 1.0447x over previous
//
#include <hip/hip_runtime.h>
#include <hip/hip_bf16.h>
#include <math.h>

#define BATCH 2
#define CC    256
#define NN    4096
#define KK    409          // max(1, int(0.1*4096))
#define KCAT  768          // split-fp16 concat K (compensated product — REQUIRED,
                           // r5 showed dropping it fails tolerance: 0.0127 > 0.0117)
#define SCALE 0.0625f      // 1/sqrt(256)
#define PSTRIDE 4096       // P row stride in halfs (P row aliases fp16 S row exactly)

typedef _Float16 half8 __attribute__((ext_vector_type(8)));
typedef float    floatx4 __attribute__((ext_vector_type(4)));

// async global->LDS, 16B per lane; LDS dest = wave-uniform base + lane*16
typedef __attribute__((address_space(3))) unsigned       lds_u32;
typedef __attribute__((address_space(1))) const unsigned glb_u32;
__device__ __forceinline__ void gload16(const void* g, void* l) {
    __builtin_amdgcn_global_load_lds((glb_u32*)g, (lds_u32*)l, 16, 0, 0);
}

// ---------- kernel 1: xpose (by<4) + wcat (by==4) merged ----------
__global__ __launch_bounds__(256) void xpose_wcat_kernel(
        const float* __restrict__ x,
        const float* __restrict__ Wq, const float* __restrict__ Wk,
        const float* __restrict__ Wv,
        _Float16* __restrict__ xcat, _Float16* __restrict__ Wcat) {
    const int t  = threadIdx.x;
    if (blockIdx.y == 4) {
        int idx = (blockIdx.z * 64 + blockIdx.x) * 256 + t;
#pragma unroll
        for (int k = 0; k < 6; k++) {
            int e = idx + k * 32768;              // covers 3*65536 exactly
            int mat = e >> 16;
            int o   = (e >> 8) & 255;
            int c   = e & 255;
            const float* W = (mat == 0) ? Wq : (mat == 1) ? Wk : Wv;
            float v = W[o * 256 + c];
            _Float16 hi = (_Float16)v;
            _Float16 lo = (_Float16)(v - (float)hi);
            _Float16* wr = Wcat + ((size_t)(mat * 256 + o)) * KCAT;
            wr[c] = hi; wr[256 + c] = hi; wr[512 + c] = lo;
        }
        return;
    }

    __shared__ float xs[64][68];
    const int n0 = blockIdx.x * 64;
    const int c0 = blockIdx.y * 64;
    const int b  = blockIdx.z;

    {
        const int ci = t >> 2;
        const int j  = (t & 3) * 16;
        const float* xp = x + ((size_t)((b << 8) + c0 + ci)) * NN + n0 + j;
        float4 a0 = ((const float4*)xp)[0];
        float4 a1 = ((const float4*)xp)[1];
        float4 a2 = ((const float4*)xp)[2];
        float4 a3 = ((const float4*)xp)[3];
        *(float4*)&xs[ci][j]      = a0;
        *(float4*)&xs[ci][j + 4]  = a1;
        *(float4*)&xs[ci][j + 8]  = a2;
        *(float4*)&xs[ci][j + 12] = a3;
    }
    __syncthreads();

    const int n = t >> 2;
    const int g0 = t & 3;
    _Float16* xr = xcat + ((size_t)(b * NN + n0 + n)) * KCAT + c0;
#pragma unroll
    for (int gg = 0; gg < 2; gg++) {
        int g = g0 + gg * 4;
        half8 hi, lo;
#pragma unroll
        for (int k = 0; k < 8; k++) {
            float v = xs[g * 8 + k][n];
            _Float16 h = (_Float16)v;
            hi[k] = h;
            lo[k] = (_Float16)(v - (float)h);
        }
        *(half8*)(xr + g * 8)       = hi;
        *(half8*)(xr + 256 + g * 8) = lo;
        *(half8*)(xr + 512 + g * 8) = hi;
    }
}

// ---------- kernel 2: projections via MFMA, 128x128 tile, K=768 ----------
// 2-phase double-buffered; compensated split (KCAT=768) throughout. FROZEN.
__global__ __launch_bounds__(256) void proj_gemm(
        const _Float16* __restrict__ xcat, const _Float16* __restrict__ Wcat,
        const float* __restrict__ bq, const float* __restrict__ bk,
        const float* __restrict__ bv,
        _Float16* __restrict__ Qcat, _Float16* __restrict__ Kcat,
        _Float16* __restrict__ Vt) {
    __shared__ _Float16 As[2][128][64];
    __shared__ _Float16 Bs[2][128][64];

    const int t    = threadIdx.x;
    const int wave = t >> 6;
    const int l    = t & 63;
    const int wr   = wave >> 1;
    const int wc   = wave & 1;
    const int mat  = blockIdx.z;

    int bym, bxn;
    if (mat < 2) { bym = blockIdx.x >> 1; bxn = blockIdx.x & 1; }
    else         { bym = blockIdx.x & 1;  bxn = blockIdx.x >> 1; }

    const int lr = l >> 3;
    const int gg = (l & 7) ^ lr;

    const _Float16* At;
    const _Float16* Bt;
    if (mat < 2) {
        At = xcat + ((size_t)(bym * 128)) * KCAT;
        Bt = Wcat + ((size_t)(mat * 256 + bxn * 128)) * KCAT;
    } else {
        At = Wcat + ((size_t)(512 + bym * 128)) * KCAT;
        Bt = xcat + ((size_t)(bxn * 128)) * KCAT;
    }
    const size_t lane_off = (size_t)lr * KCAT + gg * 8;

    floatx4 acc[4][4];
#pragma unroll
    for (int i = 0; i < 4; i++)
#pragma unroll
        for (int j = 0; j < 4; j++) acc[i][j] = (floatx4)0.0f;

    const int rowA = l & 15;
    const int sg0  = (l >> 4) ^ (l & 7);
    const int sg1  = sg0 ^ 4;

    // prologue: stage K-tile 0
#pragma unroll
    for (int s = 0; s < 4; s++) {
        const int seg = wave * 4 + s;
        gload16(At + (size_t)seg * 8 * KCAT + lane_off, &As[0][seg * 8][0]);
        gload16(Bt + (size_t)seg * 8 * KCAT + lane_off, &Bs[0][seg * 8][0]);
    }
    __syncthreads();

    for (int kt = 0; kt < 12; ++kt) {
        const int cur = kt & 1;
        if (kt < 11) {
            const int kc = (kt + 1) * 64;
#pragma unroll
            for (int s = 0; s < 4; s++) {
                const int seg = wave * 4 + s;
                gload16(At + (size_t)seg * 8 * KCAT + lane_off + kc,
                        &As[cur ^ 1][seg * 8][0]);
                gload16(Bt + (size_t)seg * 8 * KCAT + lane_off + kc,
                        &Bs[cur ^ 1][seg * 8][0]);
            }
        }
#pragma unroll
        for (int ks = 0; ks < 2; ks++) {
            const int sg = ks ? sg1 : sg0;
            half8 af[4], bf[4];
#pragma unroll
            for (int mi = 0; mi < 4; mi++)
                af[mi] = *(const half8*)&As[cur][wr * 64 + mi * 16 + rowA][sg * 8];
#pragma unroll
            for (int ni = 0; ni < 4; ni++)
                bf[ni] = *(const half8*)&Bs[cur][wc * 64 + ni * 16 + rowA][sg * 8];
#pragma unroll
            for (int mi = 0; mi < 4; mi++)
#pragma unroll
                for (int ni = 0; ni < 4; ni++)
                    acc[mi][ni] = __builtin_amdgcn_mfma_f32_16x16x32_f16(
                        af[mi], bf[ni], acc[mi][ni], 0, 0, 0);
        }
        __syncthreads();
    }

    if (mat < 2) {
        const float* bias = (mat == 0) ? bq : bk;
        _Float16* Out = (mat == 0) ? Qcat : Kcat;
#pragma unroll
        for (int ni = 0; ni < 4; ni++) {
            int ch = bxn * 128 + wc * 64 + ni * 16 + (l & 15);
            float bb = bias[ch];
#pragma unroll
            for (int mi = 0; mi < 4; mi++)
#pragma unroll
                for (int rg = 0; rg < 4; rg++) {
                    int token = bym * 128 + wr * 64 + mi * 16 + (l >> 4) * 4 + rg;
                    float v = acc[mi][ni][rg] + bb;
                    _Float16 hi = (_Float16)v;
                    _Float16 lo = (_Float16)(v - (float)hi);
                    _Float16* p = Out + (size_t)token * KCAT + ch;
                    if (mat == 0) { p[0] = hi; p[256] = lo; p[512] = hi; }
                    else          { p[0] = hi; p[256] = hi; p[512] = lo; }
                }
        }
    } else {
#pragma unroll
        for (int mi = 0; mi < 4; mi++)
#pragma unroll
            for (int rg = 0; rg < 4; rg++) {
                int ch = bym * 128 + wr * 64 + mi * 16 + (l >> 4) * 4 + rg;
                float bb = bv[ch];
#pragma unroll
                for (int ni = 0; ni < 4; ni++) {
                    int col = bxn * 128 + wc * 64 + ni * 16 + (l & 15);
                    int b = col >> 12, n = col & 4095;
                    Vt[((size_t)((b << 8) + ch)) * NN + n] =
                        (_Float16)(acc[mi][ni][rg] + bb);
                }
            }
    }
}

// ---------- kernel 3: S = (Qcat @ Kcat^T) * SCALE via MFMA f16, fp16 S ----------
// r11-proven counted-vmcnt 2-phase: BK=64 double-buffer (128 KB LDS, 512 thr
// keeps 2 waves/SIMD), stage-next FIRST, vmcnt(8). FROZEN.
__global__ __launch_bounds__(512, 2) void score_gemm(
        const _Float16* __restrict__ Qcat, const _Float16* __restrict__ Kcat,
        _Float16* __restrict__ S) {
    __shared__ _Float16 As[2][256][64];   // 64 KB
    __shared__ _Float16 Bs[2][256][64];   // 64 KB

    const int t    = threadIdx.x;
    const int wave = t >> 6;             // 0..7
    const int l    = t & 63;
    const int wr   = wave >> 1;          // 0..3 (M)
    const int wc   = wave & 1;           // 0..1 (N)

    const int id  = blockIdx.x;
    const int sc  = id & 7;              // supercell == XCD (id%8 round-robin)
    const int j   = id >> 3;             // 0..63 within supercell
    const int b   = sc & 1;
    const int scq = sc >> 1;             // quadrant 0..3
    const int bxn = ((scq & 1) << 3) + (j & 7);
    const int bym = ((scq >> 1) << 3) + (j >> 3);

    const int lr = l >> 3;
    const int gg = (l & 7) ^ lr;

    const _Float16* At = Qcat + ((size_t)((b << 12) + bym * 256)) * KCAT;
    const _Float16* Bt = Kcat + ((size_t)((b << 12) + bxn * 256)) * KCAT;
    const size_t lane_off = (size_t)lr * KCAT + gg * 8;

    floatx4 acc[4][8];
#pragma unroll
    for (int i = 0; i < 4; i++)
#pragma unroll
        for (int jj = 0; jj < 8; jj++) acc[i][jj] = (floatx4)0.0f;

    const int rowA = l & 15;
    const int sg0  = (l >> 4) ^ (l & 7);
    const int sg1  = sg0 ^ 4;

    // prologue: issue K-tile 0 loads into buffer 0 (no wait here)
#pragma unroll
    for (int s = 0; s < 4; s++) {
        const int seg = wave * 4 + s;
        gload16(At + (size_t)seg * 8 * KCAT + lane_off, &As[0][seg * 8][0]);
        gload16(Bt + (size_t)seg * 8 * KCAT + lane_off, &Bs[0][seg * 8][0]);
    }

    for (int kt = 0; kt < 12; ++kt) {
        const int cur = kt & 1;
        // stage tile kt+1 into the other buffer (8 gload16 / thread)
        if (kt < 11) {
            const int kc = (kt + 1) * 64;
#pragma unroll
            for (int s = 0; s < 4; s++) {
                const int seg = wave * 4 + s;
                gload16(At + (size_t)seg * 8 * KCAT + lane_off + kc,
                        &As[cur ^ 1][seg * 8][0]);
                gload16(Bt + (size_t)seg * 8 * KCAT + lane_off + kc,
                        &Bs[cur ^ 1][seg * 8][0]);
            }
            // outstanding = 8 (tile kt) + 8 (tile kt+1); retire the oldest 8
            asm volatile("s_waitcnt vmcnt(8)" ::: "memory");
        } else {
            asm volatile("s_waitcnt vmcnt(0)" ::: "memory");
        }
        __builtin_amdgcn_s_barrier();          // all waves' tile-kt segs ready
        asm volatile("" ::: "memory");

#pragma unroll
        for (int ks = 0; ks < 2; ks++) {
            const int sg = ks ? sg1 : sg0;
            half8 af[4], bf[8];
#pragma unroll
            for (int mi = 0; mi < 4; mi++)
                af[mi] = *(const half8*)&As[cur][wr * 64 + mi * 16 + rowA][sg * 8];
#pragma unroll
            for (int ni = 0; ni < 8; ni++)
                bf[ni] = *(const half8*)&Bs[cur][wc * 128 + ni * 16 + rowA][sg * 8];
#pragma unroll
            for (int mi = 0; mi < 4; mi++)
#pragma unroll
                for (int ni = 0; ni < 8; ni++)
                    acc[mi][ni] = __builtin_amdgcn_mfma_f32_16x16x32_f16(
                        af[mi], bf[ni], acc[mi][ni], 0, 0, 0);
        }
        __builtin_amdgcn_s_barrier();          // reads of buf[cur] done before
        asm volatile("" ::: "memory");         // next iter overwrites it
    }

    _Float16* Sb = S + ((size_t)b << 24);   // NN*NN halfs per batch
#pragma unroll
    for (int mi = 0; mi < 4; mi++)
#pragma unroll
        for (int ni = 0; ni < 8; ni++) {
            int col = bxn * 256 + wc * 128 + ni * 16 + (l & 15);
#pragma unroll
            for (int rg = 0; rg < 4; rg++) {
                int row = bym * 256 + wr * 64 + mi * 16 + (l >> 4) * 4 + rg;
                Sb[((size_t)row << 12) + col] =
                    (_Float16)(acc[mi][ni][rg] * SCALE);
            }
        }
}

// ---------- kernel 4: per-row exact top-k + softmax -> dense fp16 P row ----------
// REVERTED to r12-proven (63.0 µs): u32 zero-extended key16 + precomputed
// val[16] (r13's packed-key/recompute variant ADDED VALU and regressed
// 63->73). Wave-scan compaction, parallel level-2 rank, one-pass low-byte
// fallback. Selection set, tie-break, P bit-identical throughout.
__global__ __launch_bounds__(256) void select_scatter(
        const _Float16* __restrict__ S, _Float16* __restrict__ P) {
    __shared__ unsigned hist[256];
    __shared__ unsigned scan[256];
    __shared__ unsigned candKey[NN];     // worst case: all in one bin
    __shared__ unsigned wred[4];
    __shared__ float    wsum[4];
    __shared__ unsigned sh_d, sh_cntgt, sh_T;
    __shared__ int      sh_need;

    const int t = threadIdx.x;
    const int l = t & 63;
    const int w = t >> 6;

    // per-wave level-1 histograms alias candKey[0..1023] (dead until compaction)
    unsigned (*hist4)[256] = (unsigned (*)[256])candKey;

    float    val[16];
    unsigned ukey[16];    // key16 zero-extended to u32 (all math 32-bit)
    {
        const uint4* Srow = (const uint4*)
            ((const unsigned short*)(S + ((size_t)blockIdx.x << 12)) + t * 16);
        uint4 d0 = Srow[0];
        uint4 d1 = Srow[1];
        unsigned wb[8] = {d0.x, d0.y, d0.z, d0.w, d1.x, d1.y, d1.z, d1.w};
#pragma unroll
        for (int p = 0; p < 8; p++) {
            unsigned lo = wb[p] & 0xFFFFu;
            unsigned hi = wb[p] >> 16;
            ukey[2 * p]     = lo ^ ((lo & 0x8000u) ? 0xFFFFu : 0x8000u);
            ukey[2 * p + 1] = hi ^ ((hi & 0x8000u) ? 0xFFFFu : 0x8000u);
            unsigned short ls = (unsigned short)lo, hs = (unsigned short)hi;
            _Float16 lh, hh;
            __builtin_memcpy(&lh, &ls, 2);
            __builtin_memcpy(&hh, &hs, 2);
            val[2 * p]     = (float)lh;
            val[2 * p + 1] = (float)hh;
        }
    }

#pragma unroll
    for (int w2 = 0; w2 < 4; w2++) hist4[w2][t] = 0u;
    __syncthreads();

    // ---- level 1: per-wave histograms on key16 top byte ----
#pragma unroll
    for (int j = 0; j < 16; j++) atomicAdd(&hist4[w][ukey[j] >> 8], 1u);
    __syncthreads();
    // merge (same-thread write->read into find_digit, no extra sync needed)
    hist[t] = hist4[0][t] + hist4[1][t] + hist4[2][t] + hist4[3][t];

    int rem = KK;

    auto find_digit = [&](int remv) {
        unsigned v = hist[t];
#pragma unroll
        for (int off = 1; off < 64; off <<= 1) {
            unsigned o = __shfl_down(v, off);
            if (l + off < 64) v += o;
        }
        if (l == 0) wred[w] = v;
        __syncthreads();
        unsigned add = 0u;
#pragma unroll
        for (int w2 = 0; w2 < 4; w2++) if (w2 > w) add += wred[w2];
        scan[t] = v + add;
        __syncthreads();
        unsigned sufd  = scan[t];
        unsigned sufd1 = (t < 255) ? scan[t + 1] : 0u;
        if (sufd >= (unsigned)remv && sufd1 < (unsigned)remv) {
            sh_d = (unsigned)t; sh_cntgt = sufd1;
        }
        __syncthreads();
    };

    find_digit(rem);
    const unsigned dbin = sh_d;
    rem -= (int)sh_cntgt;

    // ---- compaction via wave-scan (no serialized atomics) ----
    int cnt = 0;
#pragma unroll
    for (int j = 0; j < 16; j++) if ((ukey[j] >> 8) == dbin) cnt++;
    int pre = cnt;
#pragma unroll
    for (int off = 1; off < 64; off <<= 1) {
        int o = __shfl_up(pre, off);
        if (l >= off) pre += o;
    }
    if (l == 63) wred[w] = (unsigned)pre;    // wave totals
    __syncthreads();
    int base = 0;
#pragma unroll
    for (int w2 = 0; w2 < 4; w2++) if (w2 < w) base += (int)wred[w2];
    const int nc = (int)(wred[0] + wred[1] + wred[2] + wred[3]);
    int slot = base + pre - cnt;             // global exclusive prefix
#pragma unroll
    for (int j = 0; j < 16; j++)
        if ((ukey[j] >> 8) == dbin) candKey[slot++] = ukey[j];
    __syncthreads();

    // ---- level 2: exact rem-th largest among candidates ----
    if (nc <= 256) {
        // parallel per-candidate rank: thread i owns candidate i
        if (t < nc) {
            const unsigned ki = candKey[t];
            int g = 0, m = 0;
            for (int j = 0; j < nc; j++) {
                unsigned kj = candKey[j];      // LDS broadcast (no conflict)
                g += (kj > ki) ? 1 : 0;
                m += (kj == ki) ? 1 : 0;
            }
            if (g < rem && g + m >= rem) {     // value-determined: benign race
                sh_T = ki; sh_need = rem - g;
            }
        }
    } else {
        // all candidates share top byte: ONE histogram pass on the low byte
        hist[t] = 0u;
        __syncthreads();
        for (int i = t; i < nc; i += 256)
            atomicAdd(&hist[candKey[i] & 255u], 1u);
        __syncthreads();
        find_digit(rem);
        if (t == 0) { sh_T = (dbin << 8) | sh_d; sh_need = rem - (int)sh_cntgt; }
    }
    __syncthreads();
    const unsigned Tk = sh_T;                  // key16 in low bits
    const int need = sh_need;
    float mT;
    {
        unsigned tu = (Tk & 0x8000u) ? (Tk ^ 0x8000u) : (~Tk & 0xFFFFu);
        unsigned short ts = (unsigned short)tu;
        _Float16 th;
        __builtin_memcpy(&th, &ts, 2);
        mT = (float)th;   // softmax shift: shift-invariant, any m works
    }

    // stable tie-break: exclusive prefix of per-thread equal counts (wave scan)
    int eqc = 0;
#pragma unroll
    for (int j = 0; j < 16; j++) if (ukey[j] == Tk) eqc++;
    int vinc = eqc;
#pragma unroll
    for (int off = 1; off < 64; off <<= 1) {
        int o = __shfl_up(vinc, off);
        if (l >= off) vinc += o;
    }
    if (l == 63) wred[w] = (unsigned)vinc;
    __syncthreads();
    int addlow = 0;
#pragma unroll
    for (int w2 = 0; w2 < 4; w2++) if (w2 < w) addlow += (int)wred[w2];
    const int eqexcl = vinc - eqc + addlow;

    // selection + exp: key>Tk unconditional, ties = exp(0) = 1.0f exactly
    float pv[16];
    float le = 0.f;
#pragma unroll
    for (int j = 0; j < 16; j++) {
        float e = 0.f;
        if (ukey[j] > Tk) { e = __expf(val[j] - mT); le += e; }
        pv[j] = e;
    }
    if (eqc) {
        int seen = 0;
#pragma unroll
        for (int j = 0; j < 16; j++) {
            if (ukey[j] == Tk) {
                if (eqexcl + seen < need) { pv[j] = 1.0f; le += 1.0f; }
                seen++;
            }
        }
    }

    // sum reduce
#pragma unroll
    for (int off = 32; off > 0; off >>= 1) {
        float o = __shfl_down(le, off);
        if (l + off < 64) le += o;
    }
    if (l == 0) wsum[w] = le;
    __syncthreads();
    const float inv = 1.0f / (wsum[0] + wsum[1] + wsum[2] + wsum[3]);

    half8 ra, rb;
#pragma unroll
    for (int j = 0; j < 8; j++) {
        ra[j] = (_Float16)(pv[j] * inv);
        rb[j] = (_Float16)(pv[j + 8] * inv);
    }
    _Float16* Pr = P + (size_t)blockIdx.x * PSTRIDE + t * 16;
    *(half8*)Pr       = ra;
    *(half8*)(Pr + 8) = rb;
}

// ---------- kernel 5: out[b][c][n] = sum_m Vt[c][m] * P[n][m] via MFMA f16 ----------
// r9-proven: BK=256 single-buffered (4 x 64x64 K-chunks, 64 KB LDS,
// 2 blocks/CU = 2 waves/SIMD). FROZEN (r12's 128 KB dbuf fell to
// 1 wave/SIMD and regressed ~15 µs).
__global__ __launch_bounds__(256) void av_gemm(
        const _Float16* __restrict__ Vt, const _Float16* __restrict__ P,
        float* __restrict__ out) {
    __shared__ _Float16 As[4][64][64];
    __shared__ _Float16 Bs[4][64][64];

    const int t    = threadIdx.x;
    const int wave = t >> 6;
    const int l    = t & 63;
    const int wr   = wave >> 1;
    const int wc   = wave & 1;
    const int bxn  = blockIdx.x;
    const int byc  = blockIdx.y;
    const int b    = blockIdx.z;

    const int lr = l >> 3;
    const int gg = (l & 7) ^ lr;

    const _Float16* At = Vt + ((size_t)((b << 8) + byc * 64)) * NN;
    const _Float16* Bt = P + ((size_t)(b * NN + bxn * 64)) * PSTRIDE;
    const size_t lane_offA = (size_t)lr * NN + gg * 8;
    const size_t lane_offB = (size_t)lr * PSTRIDE + gg * 8;

    floatx4 acc[2][2];
#pragma unroll
    for (int i = 0; i < 2; i++)
#pragma unroll
        for (int j = 0; j < 2; j++) acc[i][j] = (floatx4)0.0f;

    const int rowA   = l & 15;
    const int sgbase = (l >> 4) ^ (l & 7);

    for (int kt = 0; kt < 16; ++kt) {
        const int kc = kt * 256;
#pragma unroll
        for (int c = 0; c < 4; c++)
#pragma unroll
            for (int s = 0; s < 2; s++) {
                const int seg = wave * 2 + s;
                gload16(At + (size_t)seg * 8 * NN + lane_offA + kc + c * 64,
                        &As[c][seg * 8][0]);
                gload16(Bt + (size_t)seg * 8 * PSTRIDE + lane_offB + kc + c * 64,
                        &Bs[c][seg * 8][0]);
            }
        __syncthreads();
#pragma unroll
        for (int c = 0; c < 4; c++)
#pragma unroll
            for (int st = 0; st < 2; st++) {
                const int sg = sgbase ^ (st ? 4 : 0);
                half8 af[2], bf[2];
#pragma unroll
                for (int mi = 0; mi < 2; mi++)
                    af[mi] = *(const half8*)&As[c][wr * 32 + mi * 16 + rowA][sg * 8];
#pragma unroll
                for (int ni = 0; ni < 2; ni++)
                    bf[ni] = *(const half8*)&Bs[c][wc * 32 + ni * 16 + rowA][sg * 8];
#pragma unroll
                for (int mi = 0; mi < 2; mi++)
#pragma unroll
                    for (int ni = 0; ni < 2; ni++)
                        acc[mi][ni] = __builtin_amdgcn_mfma_f32_16x16x32_f16(
                            af[mi], bf[ni], acc[mi][ni], 0, 0, 0);
            }
        __syncthreads();
    }

#pragma unroll
    for (int mi = 0; mi < 2; mi++)
#pragma unroll
        for (int ni = 0; ni < 2; ni++) {
            int col = bxn * 64 + wc * 32 + ni * 16 + (l & 15);
#pragma unroll
            for (int rg = 0; rg < 4; rg++) {
                int row = byc * 64 + wr * 32 + mi * 16 + (l >> 4) * 4 + rg;
                out[((size_t)((b << 8) + row) << 12) + col] = acc[mi][ni][rg];
            }
        }
}

extern "C" void kernel_launch(void* const* d_in, const int* in_sizes, int n_in,
                              void* d_out, int out_size, void* d_ws, size_t ws_size,
                              hipStream_t stream) {
    const float* x  = (const float*)d_in[0];
    const float* Wq = (const float*)d_in[1];
    const float* bq = (const float*)d_in[2];
    const float* Wk = (const float*)d_in[3];
    const float* bk = (const float*)d_in[4];
    const float* Wv = (const float*)d_in[5];
    const float* bv = (const float*)d_in[6];
    float* out = (float*)d_out;

    char* ws = (char*)d_ws;
    _Float16* Wcat = (_Float16*)ws;                            // 1.18 MB
    _Float16* Qcat = (_Float16*)(ws + 1179648);                // 12.6 MB
    _Float16* Kcat = (_Float16*)(ws + 1179648 + 12582912);     // 12.6 MB
    _Float16* Vt   = (_Float16*)(ws + 1179648 + 2 * 12582912); // 4 MB
    _Float16* S    = (_Float16*)(ws + 1179648 + 2 * 12582912 + 4194304); // 64 MB fp16
    _Float16* xcat = (_Float16*)S;   // xcat dead before score_gemm writes S
    _Float16* P    = (_Float16*)S;   // P row aliases fp16 S row exactly (8 KB)

    xpose_wcat_kernel<<<dim3(64, 5, BATCH), 256, 0, stream>>>(x, Wq, Wk, Wv,
                                                              xcat, Wcat);
    proj_gemm<<<dim3(128, 1, 3), 256, 0, stream>>>(xcat, Wcat, bq, bk, bv,
                                                   Qcat, Kcat, Vt);
    score_gemm<<<dim3(512, 1, 1), 512, 0, stream>>>(Qcat, Kcat, S);
    select_scatter<<<BATCH * NN, 256, 0, stream>>>(S, P);
    av_gemm<<<dim3(64, 4, BATCH), 256, 0, stream>>>(Vt, P, out);
}

// Round 15
// 232.261 us; speedup vs baseline: 1.0836x; 1.0000x over previous
//
#include <hip/hip_runtime.h>
#include <hip/hip_bf16.h>
#include <math.h>

#define BATCH 2
#define CC    256
#define NN    4096
#define KK    409          // max(1, int(0.1*4096))
#define KCAT  768          // split-fp16 concat K (compensated product — REQUIRED,
                           // r5 showed dropping it fails tolerance: 0.0127 > 0.0117)
#define SCALE 0.0625f      // 1/sqrt(256)
#define PSTRIDE 4096       // P row stride in halfs (P row aliases fp16 S row exactly)

typedef _Float16 half8 __attribute__((ext_vector_type(8)));
typedef float    floatx4 __attribute__((ext_vector_type(4)));

// async global->LDS, 16B per lane; LDS dest = wave-uniform base + lane*16
typedef __attribute__((address_space(3))) unsigned       lds_u32;
typedef __attribute__((address_space(1))) const unsigned glb_u32;
__device__ __forceinline__ void gload16(const void* g, void* l) {
    __builtin_amdgcn_global_load_lds((glb_u32*)g, (lds_u32*)l, 16, 0, 0);
}

// ---------- kernel 1: xpose (by<4) + wcat (by==4) merged ----------
__global__ __launch_bounds__(256) void xpose_wcat_kernel(
        const float* __restrict__ x,
        const float* __restrict__ Wq, const float* __restrict__ Wk,
        const float* __restrict__ Wv,
        _Float16* __restrict__ xcat, _Float16* __restrict__ Wcat) {
    const int t  = threadIdx.x;
    if (blockIdx.y == 4) {
        int idx = (blockIdx.z * 64 + blockIdx.x) * 256 + t;
#pragma unroll
        for (int k = 0; k < 6; k++) {
            int e = idx + k * 32768;              // covers 3*65536 exactly
            int mat = e >> 16;
            int o   = (e >> 8) & 255;
            int c   = e & 255;
            const float* W = (mat == 0) ? Wq : (mat == 1) ? Wk : Wv;
            float v = W[o * 256 + c];
            _Float16 hi = (_Float16)v;
            _Float16 lo = (_Float16)(v - (float)hi);
            _Float16* wr = Wcat + ((size_t)(mat * 256 + o)) * KCAT;
            wr[c] = hi; wr[256 + c] = hi; wr[512 + c] = lo;
        }
        return;
    }

    __shared__ float xs[64][68];
    const int n0 = blockIdx.x * 64;
    const int c0 = blockIdx.y * 64;
    const int b  = blockIdx.z;

    {
        const int ci = t >> 2;
        const int j  = (t & 3) * 16;
        const float* xp = x + ((size_t)((b << 8) + c0 + ci)) * NN + n0 + j;
        float4 a0 = ((const float4*)xp)[0];
        float4 a1 = ((const float4*)xp)[1];
        float4 a2 = ((const float4*)xp)[2];
        float4 a3 = ((const float4*)xp)[3];
        *(float4*)&xs[ci][j]      = a0;
        *(float4*)&xs[ci][j + 4]  = a1;
        *(float4*)&xs[ci][j + 8]  = a2;
        *(float4*)&xs[ci][j + 12] = a3;
    }
    __syncthreads();

    const int n = t >> 2;
    const int g0 = t & 3;
    _Float16* xr = xcat + ((size_t)(b * NN + n0 + n)) * KCAT + c0;
#pragma unroll
    for (int gg = 0; gg < 2; gg++) {
        int g = g0 + gg * 4;
        half8 hi, lo;
#pragma unroll
        for (int k = 0; k < 8; k++) {
            float v = xs[g * 8 + k][n];
            _Float16 h = (_Float16)v;
            hi[k] = h;
            lo[k] = (_Float16)(v - (float)h);
        }
        *(half8*)(xr + g * 8)       = hi;
        *(half8*)(xr + 256 + g * 8) = lo;
        *(half8*)(xr + 512 + g * 8) = hi;
    }
}

// ---------- kernel 2: projections via MFMA, 128x128 tile, K=768 ----------
// 2-phase double-buffered; compensated split (KCAT=768) throughout. FROZEN.
__global__ __launch_bounds__(256) void proj_gemm(
        const _Float16* __restrict__ xcat, const _Float16* __restrict__ Wcat,
        const float* __restrict__ bq, const float* __restrict__ bk,
        const float* __restrict__ bv,
        _Float16* __restrict__ Qcat, _Float16* __restrict__ Kcat,
        _Float16* __restrict__ Vt) {
    __shared__ _Float16 As[2][128][64];
    __shared__ _Float16 Bs[2][128][64];

    const int t    = threadIdx.x;
    const int wave = t >> 6;
    const int l    = t & 63;
    const int wr   = wave >> 1;
    const int wc   = wave & 1;
    const int mat  = blockIdx.z;

    int bym, bxn;
    if (mat < 2) { bym = blockIdx.x >> 1; bxn = blockIdx.x & 1; }
    else         { bym = blockIdx.x & 1;  bxn = blockIdx.x >> 1; }

    const int lr = l >> 3;
    const int gg = (l & 7) ^ lr;

    const _Float16* At;
    const _Float16* Bt;
    if (mat < 2) {
        At = xcat + ((size_t)(bym * 128)) * KCAT;
        Bt = Wcat + ((size_t)(mat * 256 + bxn * 128)) * KCAT;
    } else {
        At = Wcat + ((size_t)(512 + bym * 128)) * KCAT;
        Bt = xcat + ((size_t)(bxn * 128)) * KCAT;
    }
    const size_t lane_off = (size_t)lr * KCAT + gg * 8;

    floatx4 acc[4][4];
#pragma unroll
    for (int i = 0; i < 4; i++)
#pragma unroll
        for (int j = 0; j < 4; j++) acc[i][j] = (floatx4)0.0f;

    const int rowA = l & 15;
    const int sg0  = (l >> 4) ^ (l & 7);
    const int sg1  = sg0 ^ 4;

    // prologue: stage K-tile 0
#pragma unroll
    for (int s = 0; s < 4; s++) {
        const int seg = wave * 4 + s;
        gload16(At + (size_t)seg * 8 * KCAT + lane_off, &As[0][seg * 8][0]);
        gload16(Bt + (size_t)seg * 8 * KCAT + lane_off, &Bs[0][seg * 8][0]);
    }
    __syncthreads();

    for (int kt = 0; kt < 12; ++kt) {
        const int cur = kt & 1;
        if (kt < 11) {
            const int kc = (kt + 1) * 64;
#pragma unroll
            for (int s = 0; s < 4; s++) {
                const int seg = wave * 4 + s;
                gload16(At + (size_t)seg * 8 * KCAT + lane_off + kc,
                        &As[cur ^ 1][seg * 8][0]);
                gload16(Bt + (size_t)seg * 8 * KCAT + lane_off + kc,
                        &Bs[cur ^ 1][seg * 8][0]);
            }
        }
#pragma unroll
        for (int ks = 0; ks < 2; ks++) {
            const int sg = ks ? sg1 : sg0;
            half8 af[4], bf[4];
#pragma unroll
            for (int mi = 0; mi < 4; mi++)
                af[mi] = *(const half8*)&As[cur][wr * 64 + mi * 16 + rowA][sg * 8];
#pragma unroll
            for (int ni = 0; ni < 4; ni++)
                bf[ni] = *(const half8*)&Bs[cur][wc * 64 + ni * 16 + rowA][sg * 8];
#pragma unroll
            for (int mi = 0; mi < 4; mi++)
#pragma unroll
                for (int ni = 0; ni < 4; ni++)
                    acc[mi][ni] = __builtin_amdgcn_mfma_f32_16x16x32_f16(
                        af[mi], bf[ni], acc[mi][ni], 0, 0, 0);
        }
        __syncthreads();
    }

    if (mat < 2) {
        const float* bias = (mat == 0) ? bq : bk;
        _Float16* Out = (mat == 0) ? Qcat : Kcat;
#pragma unroll
        for (int ni = 0; ni < 4; ni++) {
            int ch = bxn * 128 + wc * 64 + ni * 16 + (l & 15);
            float bb = bias[ch];
#pragma unroll
            for (int mi = 0; mi < 4; mi++)
#pragma unroll
                for (int rg = 0; rg < 4; rg++) {
                    int token = bym * 128 + wr * 64 + mi * 16 + (l >> 4) * 4 + rg;
                    float v = acc[mi][ni][rg] + bb;
                    _Float16 hi = (_Float16)v;
                    _Float16 lo = (_Float16)(v - (float)hi);
                    _Float16* p = Out + (size_t)token * KCAT + ch;
                    if (mat == 0) { p[0] = hi; p[256] = lo; p[512] = hi; }
                    else          { p[0] = hi; p[256] = hi; p[512] = lo; }
                }
        }
    } else {
#pragma unroll
        for (int mi = 0; mi < 4; mi++)
#pragma unroll
            for (int rg = 0; rg < 4; rg++) {
                int ch = bym * 128 + wr * 64 + mi * 16 + (l >> 4) * 4 + rg;
                float bb = bv[ch];
#pragma unroll
                for (int ni = 0; ni < 4; ni++) {
                    int col = bxn * 128 + wc * 64 + ni * 16 + (l & 15);
                    int b = col >> 12, n = col & 4095;
                    Vt[((size_t)((b << 8) + ch)) * NN + n] =
                        (_Float16)(acc[mi][ni][rg] + bb);
                }
            }
    }
}

// ---------- kernel 3: S = (Qcat @ Kcat^T) * SCALE via MFMA f16, fp16 S ----------
// r11-proven counted-vmcnt 2-phase: BK=64 double-buffer (128 KB LDS, 512 thr
// keeps 2 waves/SIMD), stage-next FIRST, vmcnt(8). FROZEN.
__global__ __launch_bounds__(512, 2) void score_gemm(
        const _Float16* __restrict__ Qcat, const _Float16* __restrict__ Kcat,
        _Float16* __restrict__ S) {
    __shared__ _Float16 As[2][256][64];   // 64 KB
    __shared__ _Float16 Bs[2][256][64];   // 64 KB

    const int t    = threadIdx.x;
    const int wave = t >> 6;             // 0..7
    const int l    = t & 63;
    const int wr   = wave >> 1;          // 0..3 (M)
    const int wc   = wave & 1;           // 0..1 (N)

    const int id  = blockIdx.x;
    const int sc  = id & 7;              // supercell == XCD (id%8 round-robin)
    const int j   = id >> 3;             // 0..63 within supercell
    const int b   = sc & 1;
    const int scq = sc >> 1;             // quadrant 0..3
    const int bxn = ((scq & 1) << 3) + (j & 7);
    const int bym = ((scq >> 1) << 3) + (j >> 3);

    const int lr = l >> 3;
    const int gg = (l & 7) ^ lr;

    const _Float16* At = Qcat + ((size_t)((b << 12) + bym * 256)) * KCAT;
    const _Float16* Bt = Kcat + ((size_t)((b << 12) + bxn * 256)) * KCAT;
    const size_t lane_off = (size_t)lr * KCAT + gg * 8;

    floatx4 acc[4][8];
#pragma unroll
    for (int i = 0; i < 4; i++)
#pragma unroll
        for (int jj = 0; jj < 8; jj++) acc[i][jj] = (floatx4)0.0f;

    const int rowA = l & 15;
    const int sg0  = (l >> 4) ^ (l & 7);
    const int sg1  = sg0 ^ 4;

    // prologue: issue K-tile 0 loads into buffer 0 (no wait here)
#pragma unroll
    for (int s = 0; s < 4; s++) {
        const int seg = wave * 4 + s;
        gload16(At + (size_t)seg * 8 * KCAT + lane_off, &As[0][seg * 8][0]);
        gload16(Bt + (size_t)seg * 8 * KCAT + lane_off, &Bs[0][seg * 8][0]);
    }

    for (int kt = 0; kt < 12; ++kt) {
        const int cur = kt & 1;
        // stage tile kt+1 into the other buffer (8 gload16 / thread)
        if (kt < 11) {
            const int kc = (kt + 1) * 64;
#pragma unroll
            for (int s = 0; s < 4; s++) {
                const int seg = wave * 4 + s;
                gload16(At + (size_t)seg * 8 * KCAT + lane_off + kc,
                        &As[cur ^ 1][seg * 8][0]);
                gload16(Bt + (size_t)seg * 8 * KCAT + lane_off + kc,
                        &Bs[cur ^ 1][seg * 8][0]);
            }
            // outstanding = 8 (tile kt) + 8 (tile kt+1); retire the oldest 8
            asm volatile("s_waitcnt vmcnt(8)" ::: "memory");
        } else {
            asm volatile("s_waitcnt vmcnt(0)" ::: "memory");
        }
        __builtin_amdgcn_s_barrier();          // all waves' tile-kt segs ready
        asm volatile("" ::: "memory");

#pragma unroll
        for (int ks = 0; ks < 2; ks++) {
            const int sg = ks ? sg1 : sg0;
            half8 af[4], bf[8];
#pragma unroll
            for (int mi = 0; mi < 4; mi++)
                af[mi] = *(const half8*)&As[cur][wr * 64 + mi * 16 + rowA][sg * 8];
#pragma unroll
            for (int ni = 0; ni < 8; ni++)
                bf[ni] = *(const half8*)&Bs[cur][wc * 128 + ni * 16 + rowA][sg * 8];
#pragma unroll
            for (int mi = 0; mi < 4; mi++)
#pragma unroll
                for (int ni = 0; ni < 8; ni++)
                    acc[mi][ni] = __builtin_amdgcn_mfma_f32_16x16x32_f16(
                        af[mi], bf[ni], acc[mi][ni], 0, 0, 0);
        }
        __builtin_amdgcn_s_barrier();          // reads of buf[cur] done before
        asm volatile("" ::: "memory");         // next iter overwrites it
    }

    _Float16* Sb = S + ((size_t)b << 24);   // NN*NN halfs per batch
#pragma unroll
    for (int mi = 0; mi < 4; mi++)
#pragma unroll
        for (int ni = 0; ni < 8; ni++) {
            int col = bxn * 256 + wc * 128 + ni * 16 + (l & 15);
#pragma unroll
            for (int rg = 0; rg < 4; rg++) {
                int row = bym * 256 + wr * 64 + mi * 16 + (l >> 4) * 4 + rg;
                Sb[((size_t)row << 12) + col] =
                    (_Float16)(acc[mi][ni][rg] * SCALE);
            }
        }
}

// ---------- kernel 4: per-row exact top-k + softmax -> dense fp16 P row ----------
// r12/r14-proven algorithm, UNCHANGED. Single new variable:
// __launch_bounds__(256, 4) — r14 showed VGPR_Count=32 with 48+ live array
// values and NO scratch traffic => allocator squeezed to a max-occupancy
// target and rematerializes val[]/ukey[] from the packed loads in every
// consuming phase (recompute VALU; r13 showed this kernel is hypersensitive
// to exactly that). min 4 waves/EU caps VGPR at 128 (>=16 waves/CU, near
// current ~20) and frees the allocator to keep arrays live. Output
// bit-identical.
__global__ __launch_bounds__(256, 4) void select_scatter(
        const _Float16* __restrict__ S, _Float16* __restrict__ P) {
    __shared__ unsigned hist[256];
    __shared__ unsigned scan[256];
    __shared__ unsigned candKey[NN];     // worst case: all in one bin
    __shared__ unsigned wred[4];
    __shared__ float    wsum[4];
    __shared__ unsigned sh_d, sh_cntgt, sh_T;
    __shared__ int      sh_need;

    const int t = threadIdx.x;
    const int l = t & 63;
    const int w = t >> 6;

    // per-wave level-1 histograms alias candKey[0..1023] (dead until compaction)
    unsigned (*hist4)[256] = (unsigned (*)[256])candKey;

    float    val[16];
    unsigned ukey[16];    // key16 zero-extended to u32 (all math 32-bit)
    {
        const uint4* Srow = (const uint4*)
            ((const unsigned short*)(S + ((size_t)blockIdx.x << 12)) + t * 16);
        uint4 d0 = Srow[0];
        uint4 d1 = Srow[1];
        unsigned wb[8] = {d0.x, d0.y, d0.z, d0.w, d1.x, d1.y, d1.z, d1.w};
#pragma unroll
        for (int p = 0; p < 8; p++) {
            unsigned lo = wb[p] & 0xFFFFu;
            unsigned hi = wb[p] >> 16;
            ukey[2 * p]     = lo ^ ((lo & 0x8000u) ? 0xFFFFu : 0x8000u);
            ukey[2 * p + 1] = hi ^ ((hi & 0x8000u) ? 0xFFFFu : 0x8000u);
            unsigned short ls = (unsigned short)lo, hs = (unsigned short)hi;
            _Float16 lh, hh;
            __builtin_memcpy(&lh, &ls, 2);
            __builtin_memcpy(&hh, &hs, 2);
            val[2 * p]     = (float)lh;
            val[2 * p + 1] = (float)hh;
        }
    }

#pragma unroll
    for (int w2 = 0; w2 < 4; w2++) hist4[w2][t] = 0u;
    __syncthreads();

    // ---- level 1: per-wave histograms on key16 top byte ----
#pragma unroll
    for (int j = 0; j < 16; j++) atomicAdd(&hist4[w][ukey[j] >> 8], 1u);
    __syncthreads();
    // merge (same-thread write->read into find_digit, no extra sync needed)
    hist[t] = hist4[0][t] + hist4[1][t] + hist4[2][t] + hist4[3][t];

    int rem = KK;

    auto find_digit = [&](int remv) {
        unsigned v = hist[t];
#pragma unroll
        for (int off = 1; off < 64; off <<= 1) {
            unsigned o = __shfl_down(v, off);
            if (l + off < 64) v += o;
        }
        if (l == 0) wred[w] = v;
        __syncthreads();
        unsigned add = 0u;
#pragma unroll
        for (int w2 = 0; w2 < 4; w2++) if (w2 > w) add += wred[w2];
        scan[t] = v + add;
        __syncthreads();
        unsigned sufd  = scan[t];
        unsigned sufd1 = (t < 255) ? scan[t + 1] : 0u;
        if (sufd >= (unsigned)remv && sufd1 < (unsigned)remv) {
            sh_d = (unsigned)t; sh_cntgt = sufd1;
        }
        __syncthreads();
    };

    find_digit(rem);
    const unsigned dbin = sh_d;
    rem -= (int)sh_cntgt;

    // ---- compaction via wave-scan (no serialized atomics) ----
    int cnt = 0;
#pragma unroll
    for (int j = 0; j < 16; j++) if ((ukey[j] >> 8) == dbin) cnt++;
    int pre = cnt;
#pragma unroll
    for (int off = 1; off < 64; off <<= 1) {
        int o = __shfl_up(pre, off);
        if (l >= off) pre += o;
    }
    if (l == 63) wred[w] = (unsigned)pre;    // wave totals
    __syncthreads();
    int base = 0;
#pragma unroll
    for (int w2 = 0; w2 < 4; w2++) if (w2 < w) base += (int)wred[w2];
    const int nc = (int)(wred[0] + wred[1] + wred[2] + wred[3]);
    int slot = base + pre - cnt;             // global exclusive prefix
#pragma unroll
    for (int j = 0; j < 16; j++)
        if ((ukey[j] >> 8) == dbin) candKey[slot++] = ukey[j];
    __syncthreads();

    // ---- level 2: exact rem-th largest among candidates ----
    if (nc <= 256) {
        // parallel per-candidate rank: thread i owns candidate i
        if (t < nc) {
            const unsigned ki = candKey[t];
            int g = 0, m = 0;
            for (int j = 0; j < nc; j++) {
                unsigned kj = candKey[j];      // LDS broadcast (no conflict)
                g += (kj > ki) ? 1 : 0;
                m += (kj == ki) ? 1 : 0;
            }
            if (g < rem && g + m >= rem) {     // value-determined: benign race
                sh_T = ki; sh_need = rem - g;
            }
        }
    } else {
        // all candidates share top byte: ONE histogram pass on the low byte
        hist[t] = 0u;
        __syncthreads();
        for (int i = t; i < nc; i += 256)
            atomicAdd(&hist[candKey[i] & 255u], 1u);
        __syncthreads();
        find_digit(rem);
        if (t == 0) { sh_T = (dbin << 8) | sh_d; sh_need = rem - (int)sh_cntgt; }
    }
    __syncthreads();
    const unsigned Tk = sh_T;                  // key16 in low bits
    const int need = sh_need;
    float mT;
    {
        unsigned tu = (Tk & 0x8000u) ? (Tk ^ 0x8000u) : (~Tk & 0xFFFFu);
        unsigned short ts = (unsigned short)tu;
        _Float16 th;
        __builtin_memcpy(&th, &ts, 2);
        mT = (float)th;   // softmax shift: shift-invariant, any m works
    }

    // stable tie-break: exclusive prefix of per-thread equal counts (wave scan)
    int eqc = 0;
#pragma unroll
    for (int j = 0; j < 16; j++) if (ukey[j] == Tk) eqc++;
    int vinc = eqc;
#pragma unroll
    for (int off = 1; off < 64; off <<= 1) {
        int o = __shfl_up(vinc, off);
        if (l >= off) vinc += o;
    }
    if (l == 63) wred[w] = (unsigned)vinc;
    __syncthreads();
    int addlow = 0;
#pragma unroll
    for (int w2 = 0; w2 < 4; w2++) if (w2 < w) addlow += (int)wred[w2];
    const int eqexcl = vinc - eqc + addlow;

    // selection + exp: key>Tk unconditional, ties = exp(0) = 1.0f exactly
    float pv[16];
    float le = 0.f;
#pragma unroll
    for (int j = 0; j < 16; j++) {
        float e = 0.f;
        if (ukey[j] > Tk) { e = __expf(val[j] - mT); le += e; }
        pv[j] = e;
    }
    if (eqc) {
        int seen = 0;
#pragma unroll
        for (int j = 0; j < 16; j++) {
            if (ukey[j] == Tk) {
                if (eqexcl + seen < need) { pv[j] = 1.0f; le += 1.0f; }
                seen++;
            }
        }
    }

    // sum reduce
#pragma unroll
    for (int off = 32; off > 0; off >>= 1) {
        float o = __shfl_down(le, off);
        if (l + off < 64) le += o;
    }
    if (l == 0) wsum[w] = le;
    __syncthreads();
    const float inv = 1.0f / (wsum[0] + wsum[1] + wsum[2] + wsum[3]);

    half8 ra, rb;
#pragma unroll
    for (int j = 0; j < 8; j++) {
        ra[j] = (_Float16)(pv[j] * inv);
        rb[j] = (_Float16)(pv[j + 8] * inv);
    }
    _Float16* Pr = P + (size_t)blockIdx.x * PSTRIDE + t * 16;
    *(half8*)Pr       = ra;
    *(half8*)(Pr + 8) = rb;
}

// ---------- kernel 5: out[b][c][n] = sum_m Vt[c][m] * P[n][m] via MFMA f16 ----------
// r9-proven: BK=256 single-buffered (4 x 64x64 K-chunks, 64 KB LDS,
// 2 blocks/CU = 2 waves/SIMD). FROZEN.
__global__ __launch_bounds__(256) void av_gemm(
        const _Float16* __restrict__ Vt, const _Float16* __restrict__ P,
        float* __restrict__ out) {
    __shared__ _Float16 As[4][64][64];
    __shared__ _Float16 Bs[4][64][64];

    const int t    = threadIdx.x;
    const int wave = t >> 6;
    const int l    = t & 63;
    const int wr   = wave >> 1;
    const int wc   = wave & 1;
    const int bxn  = blockIdx.x;
    const int byc  = blockIdx.y;
    const int b    = blockIdx.z;

    const int lr = l >> 3;
    const int gg = (l & 7) ^ lr;

    const _Float16* At = Vt + ((size_t)((b << 8) + byc * 64)) * NN;
    const _Float16* Bt = P + ((size_t)(b * NN + bxn * 64)) * PSTRIDE;
    const size_t lane_offA = (size_t)lr * NN + gg * 8;
    const size_t lane_offB = (size_t)lr * PSTRIDE + gg * 8;

    floatx4 acc[2][2];
#pragma unroll
    for (int i = 0; i < 2; i++)
#pragma unroll
        for (int j = 0; j < 2; j++) acc[i][j] = (floatx4)0.0f;

    const int rowA   = l & 15;
    const int sgbase = (l >> 4) ^ (l & 7);

    for (int kt = 0; kt < 16; ++kt) {
        const int kc = kt * 256;
#pragma unroll
        for (int c = 0; c < 4; c++)
#pragma unroll
            for (int s = 0; s < 2; s++) {
                const int seg = wave * 2 + s;
                gload16(At + (size_t)seg * 8 * NN + lane_offA + kc + c * 64,
                        &As[c][seg * 8][0]);
                gload16(Bt + (size_t)seg * 8 * PSTRIDE + lane_offB + kc + c * 64,
                        &Bs[c][seg * 8][0]);
            }
        __syncthreads();
#pragma unroll
        for (int c = 0; c < 4; c++)
#pragma unroll
            for (int st = 0; st < 2; st++) {
                const int sg = sgbase ^ (st ? 4 : 0);
                half8 af[2], bf[2];
#pragma unroll
                for (int mi = 0; mi < 2; mi++)
                    af[mi] = *(const half8*)&As[c][wr * 32 + mi * 16 + rowA][sg * 8];
#pragma unroll
                for (int ni = 0; ni < 2; ni++)
                    bf[ni] = *(const half8*)&Bs[c][wc * 32 + ni * 16 + rowA][sg * 8];
#pragma unroll
                for (int mi = 0; mi < 2; mi++)
#pragma unroll
                    for (int ni = 0; ni < 2; ni++)
                        acc[mi][ni] = __builtin_amdgcn_mfma_f32_16x16x32_f16(
                            af[mi], bf[ni], acc[mi][ni], 0, 0, 0);
            }
        __syncthreads();
    }

#pragma unroll
    for (int mi = 0; mi < 2; mi++)
#pragma unroll
        for (int ni = 0; ni < 2; ni++) {
            int col = bxn * 64 + wc * 32 + ni * 16 + (l & 15);
#pragma unroll
            for (int rg = 0; rg < 4; rg++) {
                int row = byc * 64 + wr * 32 + mi * 16 + (l >> 4) * 4 + rg;
                out[((size_t)((b << 8) + row) << 12) + col] = acc[mi][ni][rg];
            }
        }
}

extern "C" void kernel_launch(void* const* d_in, const int* in_sizes, int n_in,
                              void* d_out, int out_size, void* d_ws, size_t ws_size,
                              hipStream_t stream) {
    const float* x  = (const float*)d_in[0];
    const float* Wq = (const float*)d_in[1];
    const float* bq = (const float*)d_in[2];
    const float* Wk = (const float*)d_in[3];
    const float* bk = (const float*)d_in[4];
    const float* Wv = (const float*)d_in[5];
    const float* bv = (const float*)d_in[6];
    float* out = (float*)d_out;

    char* ws = (char*)d_ws;
    _Float16* Wcat = (_Float16*)ws;                            // 1.18 MB
    _Float16* Qcat = (_Float16*)(ws + 1179648);                // 12.6 MB
    _Float16* Kcat = (_Float16*)(ws + 1179648 + 12582912);     // 12.6 MB
    _Float16* Vt   = (_Float16*)(ws + 1179648 + 2 * 12582912); // 4 MB
    _Float16* S    = (_Float16*)(ws + 1179648 + 2 * 12582912 + 4194304); // 64 MB fp16
    _Float16* xcat = (_Float16*)S;   // xcat dead before score_gemm writes S
    _Float16* P    = (_Float16*)S;   // P row aliases fp16 S row exactly (8 KB)

    xpose_wcat_kernel<<<dim3(64, 5, BATCH), 256, 0, stream>>>(x, Wq, Wk, Wv,
                                                              xcat, Wcat);
    proj_gemm<<<dim3(128, 1, 3), 256, 0, stream>>>(xcat, Wcat, bq, bk, bv,
                                                   Qcat, Kcat, Vt);
    score_gemm<<<dim3(512, 1, 1), 512, 0, stream>>>(Qcat, Kcat, S);
    select_scatter<<<BATCH * NN, 256, 0, stream>>>(S, P);
    av_gemm<<<dim3(64, 4, BATCH), 256, 0, stream>>>(Vt, P, out);
}

// Round 17
// 213.195 us; speedup vs baseline: 1.1805x; 1.0894x over previous
//
#include <hip/hip_runtime.h>
#include <hip/hip_bf16.h>
#include <math.h>

#define BATCH 2
#define CC    256
#define NN    4096
#define KK    409          // max(1, int(0.1*4096))
#define KCAT  768          // split-fp16 concat K (compensated product — REQUIRED,
                           // r5 showed dropping it fails tolerance: 0.0127 > 0.0117)
#define SCALE 0.0625f      // 1/sqrt(256)
#define PSTRIDE 4096       // P row stride in halfs (P row aliases fp16 S row exactly)

typedef _Float16 half8 __attribute__((ext_vector_type(8)));
typedef float    floatx4 __attribute__((ext_vector_type(4)));

// async global->LDS, 16B per lane; LDS dest = wave-uniform base + lane*16
typedef __attribute__((address_space(3))) unsigned       lds_u32;
typedef __attribute__((address_space(1))) const unsigned glb_u32;
__device__ __forceinline__ void gload16(const void* g, void* l) {
    __builtin_amdgcn_global_load_lds((glb_u32*)g, (lds_u32*)l, 16, 0, 0);
}

// ---------- kernel 1: xpose (by<4) + wcat (by==4) merged ----------
__global__ __launch_bounds__(256) void xpose_wcat_kernel(
        const float* __restrict__ x,
        const float* __restrict__ Wq, const float* __restrict__ Wk,
        const float* __restrict__ Wv,
        _Float16* __restrict__ xcat, _Float16* __restrict__ Wcat) {
    const int t  = threadIdx.x;
    if (blockIdx.y == 4) {
        int idx = (blockIdx.z * 64 + blockIdx.x) * 256 + t;
#pragma unroll
        for (int k = 0; k < 6; k++) {
            int e = idx + k * 32768;              // covers 3*65536 exactly
            int mat = e >> 16;
            int o   = (e >> 8) & 255;
            int c   = e & 255;
            const float* W = (mat == 0) ? Wq : (mat == 1) ? Wk : Wv;
            float v = W[o * 256 + c];
            _Float16 hi = (_Float16)v;
            _Float16 lo = (_Float16)(v - (float)hi);
            _Float16* wr = Wcat + ((size_t)(mat * 256 + o)) * KCAT;
            wr[c] = hi; wr[256 + c] = hi; wr[512 + c] = lo;
        }
        return;
    }

    __shared__ float xs[64][68];
    const int n0 = blockIdx.x * 64;
    const int c0 = blockIdx.y * 64;
    const int b  = blockIdx.z;

    {
        const int ci = t >> 2;
        const int j  = (t & 3) * 16;
        const float* xp = x + ((size_t)((b << 8) + c0 + ci)) * NN + n0 + j;
        float4 a0 = ((const float4*)xp)[0];
        float4 a1 = ((const float4*)xp)[1];
        float4 a2 = ((const float4*)xp)[2];
        float4 a3 = ((const float4*)xp)[3];
        *(float4*)&xs[ci][j]      = a0;
        *(float4*)&xs[ci][j + 4]  = a1;
        *(float4*)&xs[ci][j + 8]  = a2;
        *(float4*)&xs[ci][j + 12] = a3;
    }
    __syncthreads();

    const int n = t >> 2;
    const int g0 = t & 3;
    _Float16* xr = xcat + ((size_t)(b * NN + n0 + n)) * KCAT + c0;
#pragma unroll
    for (int gg = 0; gg < 2; gg++) {
        int g = g0 + gg * 4;
        half8 hi, lo;
#pragma unroll
        for (int k = 0; k < 8; k++) {
            float v = xs[g * 8 + k][n];
            _Float16 h = (_Float16)v;
            hi[k] = h;
            lo[k] = (_Float16)(v - (float)h);
        }
        *(half8*)(xr + g * 8)       = hi;
        *(half8*)(xr + 256 + g * 8) = lo;
        *(half8*)(xr + 512 + g * 8) = hi;
    }
}

// ---------- kernel 2: projections via MFMA, 128x128 tile, K=768 ----------
// 2-phase double-buffered; compensated split (KCAT=768) throughout. FROZEN.
__global__ __launch_bounds__(256) void proj_gemm(
        const _Float16* __restrict__ xcat, const _Float16* __restrict__ Wcat,
        const float* __restrict__ bq, const float* __restrict__ bk,
        const float* __restrict__ bv,
        _Float16* __restrict__ Qcat, _Float16* __restrict__ Kcat,
        _Float16* __restrict__ Vt) {
    __shared__ _Float16 As[2][128][64];
    __shared__ _Float16 Bs[2][128][64];

    const int t    = threadIdx.x;
    const int wave = t >> 6;
    const int l    = t & 63;
    const int wr   = wave >> 1;
    const int wc   = wave & 1;
    const int mat  = blockIdx.z;

    int bym, bxn;
    if (mat < 2) { bym = blockIdx.x >> 1; bxn = blockIdx.x & 1; }
    else         { bym = blockIdx.x & 1;  bxn = blockIdx.x >> 1; }

    const int lr = l >> 3;
    const int gg = (l & 7) ^ lr;

    const _Float16* At;
    const _Float16* Bt;
    if (mat < 2) {
        At = xcat + ((size_t)(bym * 128)) * KCAT;
        Bt = Wcat + ((size_t)(mat * 256 + bxn * 128)) * KCAT;
    } else {
        At = Wcat + ((size_t)(512 + bym * 128)) * KCAT;
        Bt = xcat + ((size_t)(bxn * 128)) * KCAT;
    }
    const size_t lane_off = (size_t)lr * KCAT + gg * 8;

    floatx4 acc[4][4];
#pragma unroll
    for (int i = 0; i < 4; i++)
#pragma unroll
        for (int j = 0; j < 4; j++) acc[i][j] = (floatx4)0.0f;

    const int rowA = l & 15;
    const int sg0  = (l >> 4) ^ (l & 7);
    const int sg1  = sg0 ^ 4;

    // prologue: stage K-tile 0
#pragma unroll
    for (int s = 0; s < 4; s++) {
        const int seg = wave * 4 + s;
        gload16(At + (size_t)seg * 8 * KCAT + lane_off, &As[0][seg * 8][0]);
        gload16(Bt + (size_t)seg * 8 * KCAT + lane_off, &Bs[0][seg * 8][0]);
    }
    __syncthreads();

    for (int kt = 0; kt < 12; ++kt) {
        const int cur = kt & 1;
        if (kt < 11) {
            const int kc = (kt + 1) * 64;
#pragma unroll
            for (int s = 0; s < 4; s++) {
                const int seg = wave * 4 + s;
                gload16(At + (size_t)seg * 8 * KCAT + lane_off + kc,
                        &As[cur ^ 1][seg * 8][0]);
                gload16(Bt + (size_t)seg * 8 * KCAT + lane_off + kc,
                        &Bs[cur ^ 1][seg * 8][0]);
            }
        }
#pragma unroll
        for (int ks = 0; ks < 2; ks++) {
            const int sg = ks ? sg1 : sg0;
            half8 af[4], bf[4];
#pragma unroll
            for (int mi = 0; mi < 4; mi++)
                af[mi] = *(const half8*)&As[cur][wr * 64 + mi * 16 + rowA][sg * 8];
#pragma unroll
            for (int ni = 0; ni < 4; ni++)
                bf[ni] = *(const half8*)&Bs[cur][wc * 64 + ni * 16 + rowA][sg * 8];
#pragma unroll
            for (int mi = 0; mi < 4; mi++)
#pragma unroll
                for (int ni = 0; ni < 4; ni++)
                    acc[mi][ni] = __builtin_amdgcn_mfma_f32_16x16x32_f16(
                        af[mi], bf[ni], acc[mi][ni], 0, 0, 0);
        }
        __syncthreads();
    }

    if (mat < 2) {
        const float* bias = (mat == 0) ? bq : bk;
        _Float16* Out = (mat == 0) ? Qcat : Kcat;
#pragma unroll
        for (int ni = 0; ni < 4; ni++) {
            int ch = bxn * 128 + wc * 64 + ni * 16 + (l & 15);
            float bb = bias[ch];
#pragma unroll
            for (int mi = 0; mi < 4; mi++)
#pragma unroll
                for (int rg = 0; rg < 4; rg++) {
                    int token = bym * 128 + wr * 64 + mi * 16 + (l >> 4) * 4 + rg;
                    float v = acc[mi][ni][rg] + bb;
                    _Float16 hi = (_Float16)v;
                    _Float16 lo = (_Float16)(v - (float)hi);
                    _Float16* p = Out + (size_t)token * KCAT + ch;
                    if (mat == 0) { p[0] = hi; p[256] = lo; p[512] = hi; }
                    else          { p[0] = hi; p[256] = hi; p[512] = lo; }
                }
        }
    } else {
#pragma unroll
        for (int mi = 0; mi < 4; mi++)
#pragma unroll
            for (int rg = 0; rg < 4; rg++) {
                int ch = bym * 128 + wr * 64 + mi * 16 + (l >> 4) * 4 + rg;
                float bb = bv[ch];
#pragma unroll
                for (int ni = 0; ni < 4; ni++) {
                    int col = bxn * 128 + wc * 64 + ni * 16 + (l & 15);
                    int b = col >> 12, n = col & 4095;
                    Vt[((size_t)((b << 8) + ch)) * NN + n] =
                        (_Float16)(acc[mi][ni][rg] + bb);
                }
            }
    }
}

// ---------- kernel 3: S = (Qcat @ Kcat^T) * SCALE via MFMA f16, fp16 S ----------
// r11-proven counted-vmcnt 2-phase: BK=64 double-buffer (128 KB LDS, 512 thr
// keeps 2 waves/SIMD), stage-next FIRST, vmcnt(8). FROZEN.
__global__ __launch_bounds__(512, 2) void score_gemm(
        const _Float16* __restrict__ Qcat, const _Float16* __restrict__ Kcat,
        _Float16* __restrict__ S) {
    __shared__ _Float16 As[2][256][64];   // 64 KB
    __shared__ _Float16 Bs[2][256][64];   // 64 KB

    const int t    = threadIdx.x;
    const int wave = t >> 6;             // 0..7
    const int l    = t & 63;
    const int wr   = wave >> 1;          // 0..3 (M)
    const int wc   = wave & 1;           // 0..1 (N)

    const int id  = blockIdx.x;
    const int sc  = id & 7;              // supercell == XCD (id%8 round-robin)
    const int j   = id >> 3;             // 0..63 within supercell
    const int b   = sc & 1;
    const int scq = sc >> 1;             // quadrant 0..3
    const int bxn = ((scq & 1) << 3) + (j & 7);
    const int bym = ((scq >> 1) << 3) + (j >> 3);

    const int lr = l >> 3;
    const int gg = (l & 7) ^ lr;

    const _Float16* At = Qcat + ((size_t)((b << 12) + bym * 256)) * KCAT;
    const _Float16* Bt = Kcat + ((size_t)((b << 12) + bxn * 256)) * KCAT;
    const size_t lane_off = (size_t)lr * KCAT + gg * 8;

    floatx4 acc[4][8];
#pragma unroll
    for (int i = 0; i < 4; i++)
#pragma unroll
        for (int jj = 0; jj < 8; jj++) acc[i][jj] = (floatx4)0.0f;

    const int rowA = l & 15;
    const int sg0  = (l >> 4) ^ (l & 7);
    const int sg1  = sg0 ^ 4;

    // prologue: issue K-tile 0 loads into buffer 0 (no wait here)
#pragma unroll
    for (int s = 0; s < 4; s++) {
        const int seg = wave * 4 + s;
        gload16(At + (size_t)seg * 8 * KCAT + lane_off, &As[0][seg * 8][0]);
        gload16(Bt + (size_t)seg * 8 * KCAT + lane_off, &Bs[0][seg * 8][0]);
    }

    for (int kt = 0; kt < 12; ++kt) {
        const int cur = kt & 1;
        // stage tile kt+1 into the other buffer (8 gload16 / thread)
        if (kt < 11) {
            const int kc = (kt + 1) * 64;
#pragma unroll
            for (int s = 0; s < 4; s++) {
                const int seg = wave * 4 + s;
                gload16(At + (size_t)seg * 8 * KCAT + lane_off + kc,
                        &As[cur ^ 1][seg * 8][0]);
                gload16(Bt + (size_t)seg * 8 * KCAT + lane_off + kc,
                        &Bs[cur ^ 1][seg * 8][0]);
            }
            // outstanding = 8 (tile kt) + 8 (tile kt+1); retire the oldest 8
            asm volatile("s_waitcnt vmcnt(8)" ::: "memory");
        } else {
            asm volatile("s_waitcnt vmcnt(0)" ::: "memory");
        }
        __builtin_amdgcn_s_barrier();          // all waves' tile-kt segs ready
        asm volatile("" ::: "memory");

#pragma unroll
        for (int ks = 0; ks < 2; ks++) {
            const int sg = ks ? sg1 : sg0;
            half8 af[4], bf[8];
#pragma unroll
            for (int mi = 0; mi < 4; mi++)
                af[mi] = *(const half8*)&As[cur][wr * 64 + mi * 16 + rowA][sg * 8];
#pragma unroll
            for (int ni = 0; ni < 8; ni++)
                bf[ni] = *(const half8*)&Bs[cur][wc * 128 + ni * 16 + rowA][sg * 8];
#pragma unroll
            for (int mi = 0; mi < 4; mi++)
#pragma unroll
                for (int ni = 0; ni < 8; ni++)
                    acc[mi][ni] = __builtin_amdgcn_mfma_f32_16x16x32_f16(
                        af[mi], bf[ni], acc[mi][ni], 0, 0, 0);
        }
        __builtin_amdgcn_s_barrier();          // reads of buf[cur] done before
        asm volatile("" ::: "memory");         // next iter overwrites it
    }

    _Float16* Sb = S + ((size_t)b << 24);   // NN*NN halfs per batch
#pragma unroll
    for (int mi = 0; mi < 4; mi++)
#pragma unroll
        for (int ni = 0; ni < 8; ni++) {
            int col = bxn * 256 + wc * 128 + ni * 16 + (l & 15);
#pragma unroll
            for (int rg = 0; rg < 4; rg++) {
                int row = bym * 256 + wr * 64 + mi * 16 + (l >> 4) * 4 + rg;
                Sb[((size_t)row << 12) + col] =
                    (_Float16)(acc[mi][ni][rg] * SCALE);
            }
        }
}

// ---------- kernel 4: per-row exact top-k + softmax -> dense fp16 P row ----------
// NEW: 10-bit level-1 bins (1024). r15 accounting showed ~1700 VALU
// instr/wave — dominated by the level-2 rank loop (scales with nc) and
// level-1 atomic same-address serialization (S values concentrated).
// 4x narrower threshold bin => nc ~4x smaller (shorter rank loop, fallback
// rare) and 4x less atomic contention. hist4[4][1024] aliases candKey
// exactly (16 KB); merge arranged so thread t owns bins 4t..4t+3
// (same-thread write->read); group-suffix finder + 4-step walk; fallback =
// one 64-bin pass on low 6 bits (wave-0 shfl suffix). Selection total-order,
// tie-break, and P arithmetic unchanged -> bit-identical output.
__global__ __launch_bounds__(256) void select_scatter(
        const _Float16* __restrict__ S, _Float16* __restrict__ P) {
    __shared__ unsigned histm[1024];     // merged 10-bit histogram
    __shared__ unsigned scan[256];       // group suffix; fallback hist64 alias
    __shared__ unsigned candKey[NN];     // 16 KB; hist4[4][1024] aliases it
    __shared__ unsigned wred[4];
    __shared__ float    wsum[4];
    __shared__ unsigned sh_d, sh_cntgt, sh_T;
    __shared__ int      sh_need;

    const int t = threadIdx.x;
    const int l = t & 63;
    const int w = t >> 6;

    unsigned (*hist4)[1024] = (unsigned (*)[1024])candKey;

    float    val[16];
    unsigned ukey[16];    // key16 zero-extended to u32 (all math 32-bit)
    {
        const uint4* Srow = (const uint4*)
            ((const unsigned short*)(S + ((size_t)blockIdx.x << 12)) + t * 16);
        uint4 d0 = Srow[0];
        uint4 d1 = Srow[1];
        unsigned wb[8] = {d0.x, d0.y, d0.z, d0.w, d1.x, d1.y, d1.z, d1.w};
#pragma unroll
        for (int p = 0; p < 8; p++) {
            unsigned lo = wb[p] & 0xFFFFu;
            unsigned hi = wb[p] >> 16;
            ukey[2 * p]     = lo ^ ((lo & 0x8000u) ? 0xFFFFu : 0x8000u);
            ukey[2 * p + 1] = hi ^ ((hi & 0x8000u) ? 0xFFFFu : 0x8000u);
            unsigned short ls = (unsigned short)lo, hs = (unsigned short)hi;
            _Float16 lh, hh;
            __builtin_memcpy(&lh, &ls, 2);
            __builtin_memcpy(&hh, &hs, 2);
            val[2 * p]     = (float)lh;
            val[2 * p + 1] = (float)hh;
        }
    }

    // zero all 4 per-wave histograms (4096 words, strided: no bank conflict)
#pragma unroll
    for (int i = 0; i < 16; i++) candKey[t + 256 * i] = 0u;
    __syncthreads();

    // ---- level 1: per-wave histograms on key16 top 10 bits ----
#pragma unroll
    for (int j = 0; j < 16; j++) atomicAdd(&hist4[w][ukey[j] >> 6], 1u);
    __syncthreads();
    // merge: thread t owns bins 4t..4t+3 (same-thread write->read below)
#pragma unroll
    for (int i = 0; i < 4; i++) {
        int bn = 4 * t + i;
        histm[bn] = hist4[0][bn] + hist4[1][bn] + hist4[2][bn] + hist4[3][bn];
    }

    int rem = KK;

    // ---- 10-bit digit finder: group suffix over 256 groups of 4 bins ----
    {
        unsigned sloc = histm[4 * t] + histm[4 * t + 1] +
                        histm[4 * t + 2] + histm[4 * t + 3];
        unsigned v = sloc;
#pragma unroll
        for (int off = 1; off < 64; off <<= 1) {
            unsigned o = __shfl_down(v, off);
            if (l + off < 64) v += o;
        }
        if (l == 0) wred[w] = v;
        __syncthreads();
        unsigned add = 0u;
#pragma unroll
        for (int w2 = 0; w2 < 4; w2++) if (w2 > w) add += wred[w2];
        scan[t] = v + add;
        __syncthreads();
        unsigned sufd  = scan[t];
        unsigned sufd1 = (t < 255) ? scan[t + 1] : 0u;
        if (sufd >= (unsigned)rem && sufd1 < (unsigned)rem) {
            // walk this group's 4 bins from high to low
            unsigned cum = sufd1;
#pragma unroll
            for (int bb = 3; bb >= 0; bb--) {
                unsigned h = histm[4 * t + bb];
                if (cum + h >= (unsigned)rem) {
                    sh_d = (unsigned)(4 * t + bb);
                    sh_cntgt = cum;      // elements in bins strictly greater
                    break;
                }
                cum += h;
            }
        }
        __syncthreads();
    }

    const unsigned dbin = sh_d;
    rem -= (int)sh_cntgt;

    // ---- compaction via wave-scan (no serialized atomics) ----
    int cnt = 0;
#pragma unroll
    for (int j = 0; j < 16; j++) if ((ukey[j] >> 6) == dbin) cnt++;
    int pre = cnt;
#pragma unroll
    for (int off = 1; off < 64; off <<= 1) {
        int o = __shfl_up(pre, off);
        if (l >= off) pre += o;
    }
    if (l == 63) wred[w] = (unsigned)pre;    // wave totals
    __syncthreads();
    int base = 0;
#pragma unroll
    for (int w2 = 0; w2 < 4; w2++) if (w2 < w) base += (int)wred[w2];
    const int nc = (int)(wred[0] + wred[1] + wred[2] + wred[3]);
    int slot = base + pre - cnt;             // global exclusive prefix
#pragma unroll
    for (int j = 0; j < 16; j++)
        if ((ukey[j] >> 6) == dbin) candKey[slot++] = ukey[j];
    __syncthreads();

    // ---- level 2: exact rem-th largest among candidates ----
    if (nc <= 256) {
        // parallel per-candidate rank: thread i owns candidate i
        if (t < nc) {
            const unsigned ki = candKey[t];
            int g = 0, m = 0;
            for (int j = 0; j < nc; j++) {
                unsigned kj = candKey[j];      // LDS broadcast (no conflict)
                g += (kj > ki) ? 1 : 0;
                m += (kj == ki) ? 1 : 0;
            }
            if (g < rem && g + m >= rem) {     // value-determined: benign race
                sh_T = ki; sh_need = rem - g;
            }
        }
    } else {
        // candidates share top 10 bits: ONE 64-bin pass on the low 6 bits
        if (t < 64) scan[t] = 0u;
        __syncthreads();
        for (int i = t; i < nc; i += 256)
            atomicAdd(&scan[candKey[i] & 63u], 1u);
        __syncthreads();
        if (w == 0) {
            unsigned v = scan[l];
#pragma unroll
            for (int off = 1; off < 64; off <<= 1) {
                unsigned o = __shfl_down(v, off);
                if (l + off < 64) v += o;
            }
            unsigned sufd1 = __shfl_down(v, 1);
            if (l == 63) sufd1 = 0u;
            if (v >= (unsigned)rem && sufd1 < (unsigned)rem) {
                sh_T = (dbin << 6) | (unsigned)l;
                sh_need = rem - (int)sufd1;
            }
        }
    }
    __syncthreads();
    const unsigned Tk = sh_T;                  // key16 in low bits
    const int need = sh_need;
    float mT;
    {
        unsigned tu = (Tk & 0x8000u) ? (Tk ^ 0x8000u) : (~Tk & 0xFFFFu);
        unsigned short ts = (unsigned short)tu;
        _Float16 th;
        __builtin_memcpy(&th, &ts, 2);
        mT = (float)th;   // softmax shift: shift-invariant, any m works
    }

    // stable tie-break: exclusive prefix of per-thread equal counts (wave scan)
    int eqc = 0;
#pragma unroll
    for (int j = 0; j < 16; j++) if (ukey[j] == Tk) eqc++;
    int vinc = eqc;
#pragma unroll
    for (int off = 1; off < 64; off <<= 1) {
        int o = __shfl_up(vinc, off);
        if (l >= off) vinc += o;
    }
    if (l == 63) wred[w] = (unsigned)vinc;
    __syncthreads();
    int addlow = 0;
#pragma unroll
    for (int w2 = 0; w2 < 4; w2++) if (w2 < w) addlow += (int)wred[w2];
    const int eqexcl = vinc - eqc + addlow;

    // selection + exp: key>Tk unconditional, ties = exp(0) = 1.0f exactly
    float pv[16];
    float le = 0.f;
#pragma unroll
    for (int j = 0; j < 16; j++) {
        float e = 0.f;
        if (ukey[j] > Tk) { e = __expf(val[j] - mT); le += e; }
        pv[j] = e;
    }
    if (eqc) {
        int seen = 0;
#pragma unroll
        for (int j = 0; j < 16; j++) {
            if (ukey[j] == Tk) {
                if (eqexcl + seen < need) { pv[j] = 1.0f; le += 1.0f; }
                seen++;
            }
        }
    }

    // sum reduce
#pragma unroll
    for (int off = 32; off > 0; off >>= 1) {
        float o = __shfl_down(le, off);
        if (l + off < 64) le += o;
    }
    if (l == 0) wsum[w] = le;
    __syncthreads();
    const float inv = 1.0f / (wsum[0] + wsum[1] + wsum[2] + wsum[3]);

    half8 ra, rb;
#pragma unroll
    for (int j = 0; j < 8; j++) {
        ra[j] = (_Float16)(pv[j] * inv);
        rb[j] = (_Float16)(pv[j + 8] * inv);
    }
    _Float16* Pr = P + (size_t)blockIdx.x * PSTRIDE + t * 16;
    *(half8*)Pr       = ra;
    *(half8*)(Pr + 8) = rb;
}

// ---------- kernel 5: out[b][c][n] = sum_m Vt[c][m] * P[n][m] via MFMA f16 ----------
// r9-proven: BK=256 single-buffered (4 x 64x64 K-chunks, 64 KB LDS,
// 2 blocks/CU = 2 waves/SIMD). FROZEN.
__global__ __launch_bounds__(256) void av_gemm(
        const _Float16* __restrict__ Vt, const _Float16* __restrict__ P,
        float* __restrict__ out) {
    __shared__ _Float16 As[4][64][64];
    __shared__ _Float16 Bs[4][64][64];

    const int t    = threadIdx.x;
    const int wave = t >> 6;
    const int l    = t & 63;
    const int wr   = wave >> 1;
    const int wc   = wave & 1;
    const int bxn  = blockIdx.x;
    const int byc  = blockIdx.y;
    const int b    = blockIdx.z;

    const int lr = l >> 3;
    const int gg = (l & 7) ^ lr;

    const _Float16* At = Vt + ((size_t)((b << 8) + byc * 64)) * NN;
    const _Float16* Bt = P + ((size_t)(b * NN + bxn * 64)) * PSTRIDE;
    const size_t lane_offA = (size_t)lr * NN + gg * 8;
    const size_t lane_offB = (size_t)lr * PSTRIDE + gg * 8;

    floatx4 acc[2][2];
#pragma unroll
    for (int i = 0; i < 2; i++)
#pragma unroll
        for (int j = 0; j < 2; j++) acc[i][j] = (floatx4)0.0f;

    const int rowA   = l & 15;
    const int sgbase = (l >> 4) ^ (l & 7);

    for (int kt = 0; kt < 16; ++kt) {
        const int kc = kt * 256;
#pragma unroll
        for (int c = 0; c < 4; c++)
#pragma unroll
            for (int s = 0; s < 2; s++) {
                const int seg = wave * 2 + s;
                gload16(At + (size_t)seg * 8 * NN + lane_offA + kc + c * 64,
                        &As[c][seg * 8][0]);
                gload16(Bt + (size_t)seg * 8 * PSTRIDE + lane_offB + kc + c * 64,
                        &Bs[c][seg * 8][0]);
            }
        __syncthreads();
#pragma unroll
        for (int c = 0; c < 4; c++)
#pragma unroll
            for (int st = 0; st < 2; st++) {
                const int sg = sgbase ^ (st ? 4 : 0);
                half8 af[2], bf[2];
#pragma unroll
                for (int mi = 0; mi < 2; mi++)
                    af[mi] = *(const half8*)&As[c][wr * 32 + mi * 16 + rowA][sg * 8];
#pragma unroll
                for (int ni = 0; ni < 2; ni++)
                    bf[ni] = *(const half8*)&Bs[c][wc * 32 + ni * 16 + rowA][sg * 8];
#pragma unroll
                for (int mi = 0; mi < 2; mi++)
#pragma unroll
                    for (int ni = 0; ni < 2; ni++)
                        acc[mi][ni] = __builtin_amdgcn_mfma_f32_16x16x32_f16(
                            af[mi], bf[ni], acc[mi][ni], 0, 0, 0);
            }
        __syncthreads();
    }

#pragma unroll
    for (int mi = 0; mi < 2; mi++)
#pragma unroll
        for (int ni = 0; ni < 2; ni++) {
            int col = bxn * 64 + wc * 32 + ni * 16 + (l & 15);
#pragma unroll
            for (int rg = 0; rg < 4; rg++) {
                int row = byc * 64 + wr * 32 + mi * 16 + (l >> 4) * 4 + rg;
                out[((size_t)((b << 8) + row) << 12) + col] = acc[mi][ni][rg];
            }
        }
}

extern "C" void kernel_launch(void* const* d_in, const int* in_sizes, int n_in,
                              void* d_out, int out_size, void* d_ws, size_t ws_size,
                              hipStream_t stream) {
    const float* x  = (const float*)d_in[0];
    const float* Wq = (const float*)d_in[1];
    const float* bq = (const float*)d_in[2];
    const float* Wk = (const float*)d_in[3];
    const float* bk = (const float*)d_in[4];
    const float* Wv = (const float*)d_in[5];
    const float* bv = (const float*)d_in[6];
    float* out = (float*)d_out;

    char* ws = (char*)d_ws;
    _Float16* Wcat = (_Float16*)ws;                            // 1.18 MB
    _Float16* Qcat = (_Float16*)(ws + 1179648);                // 12.6 MB
    _Float16* Kcat = (_Float16*)(ws + 1179648 + 12582912);     // 12.6 MB
    _Float16* Vt   = (_Float16*)(ws + 1179648 + 2 * 12582912); // 4 MB
    _Float16* S    = (_Float16*)(ws + 1179648 + 2 * 12582912 + 4194304); // 64 MB fp16
    _Float16* xcat = (_Float16*)S;   // xcat dead before score_gemm writes S
    _Float16* P    = (_Float16*)S;   // P row aliases fp16 S row exactly (8 KB)

    xpose_wcat_kernel<<<dim3(64, 5, BATCH), 256, 0, stream>>>(x, Wq, Wk, Wv,
                                                              xcat, Wcat);
    proj_gemm<<<dim3(128, 1, 3), 256, 0, stream>>>(xcat, Wcat, bq, bk, bv,
                                                   Qcat, Kcat, Vt);
    score_gemm<<<dim3(512, 1, 1), 512, 0, stream>>>(Qcat, Kcat, S);
    select_scatter<<<BATCH * NN, 256, 0, stream>>>(S, P);
    av_gemm<<<dim3(64, 4, BATCH), 256, 0, stream>>>(Vt, P, out);
}